// Round 16
// baseline (243.139 us; speedup 1.0000x reference)
//
#include <hip/hip_runtime.h>
#include <hip/hip_bf16.h>
#include <math.h>

#define DH 1024
#define BB 4
#define NN 1024
#define NH 16
#define HD 64

typedef __attribute__((ext_vector_type(8))) short bf16x8;
typedef __attribute__((ext_vector_type(4))) float f32x4;
typedef __attribute__((ext_vector_type(4))) unsigned int u32x4;
typedef unsigned short u16;
typedef unsigned int u32;

static __device__ __forceinline__ u16 f2bf(float f) {
  __hip_bfloat16 h = __float2bfloat16(f);
  return *reinterpret_cast<u16*>(&h);
}
static __device__ __forceinline__ float bf2f(u16 x) {
  return __uint_as_float((unsigned)x << 16);
}

#define MFMA16(a, b, c) __builtin_amdgcn_mfma_f32_16x16x32_bf16(a, b, c, 0, 0, 0)
#define VMCNT(n) asm volatile("s_waitcnt vmcnt(" #n ")" ::: "memory")
#define MEMFENCE asm volatile("" ::: "memory")
#define BAR() do { __builtin_amdgcn_s_barrier(); MEMFENCE; } while (0)

static __device__ __forceinline__ void async16(const void* g, void* l) {
  __builtin_amdgcn_global_load_lds(
      (const __attribute__((address_space(1))) void*)g,
      (__attribute__((address_space(3))) void*)l, 16, 0, 0);
}

// ---------------- fused weight fp32 -> bf16 (all 4 weights, 1 launch) ----------------
__global__ void cvt_all_kernel(const float* __restrict__ wq, const float* __restrict__ wp,
                               const float* __restrict__ wu, const float* __restrict__ wd,
                               u16* __restrict__ oq, u16* __restrict__ op,
                               u16* __restrict__ ou, u16* __restrict__ od) {
  int i = blockIdx.x * 256 + threadIdx.x;  // float4 index, total 3145728
  const float* src; u16* dst; int off;
  if (i < 786432)            { src = wq; dst = oq; off = i; }
  else if (i < 1048576)      { src = wp; dst = op; off = i - 786432; }
  else if (i < 2097152)      { src = wu; dst = ou; off = i - 1048576; }
  else                       { src = wd; dst = od; off = i - 2097152; }
  float4 v = reinterpret_cast<const float4*>(src)[off];
  ushort4 o;
  o.x = f2bf(v.x); o.y = f2bf(v.y); o.z = f2bf(v.z); o.w = f2bf(v.w);
  reinterpret_cast<ushort4*>(dst)[off] = o;
}

// ---------------- adaLN small linears (4 rows of time_emb) ----------------
__global__ __launch_bounds__(256) void adaln_kernel(
    const float* __restrict__ e,
    const float* __restrict__ w_s1, const float* __restrict__ b_s1,
    const float* __restrict__ w_o1, const float* __restrict__ b_o1,
    const float* __restrict__ w_s2, const float* __restrict__ b_s2,
    const float* __restrict__ w_o2, const float* __restrict__ b_o2,
    float* __restrict__ out) {
  int tid = threadIdx.x, wid = tid >> 6, lane = tid & 63;
  int mat = blockIdx.y;
  const float* w; const float* bs; float addc;
  if (mat == 0)      { w = w_s1; bs = b_s1; addc = 1.f; }
  else if (mat == 1) { w = w_o1; bs = b_o1; addc = 0.f; }
  else if (mat == 2) { w = w_s2; bs = b_s2; addc = 1.f; }
  else               { w = w_o2; bs = b_o2; addc = 0.f; }
  int col = blockIdx.x * 4 + wid;
  float a0 = 0.f, a1 = 0.f, a2 = 0.f, a3 = 0.f;
  const float* wc_ = w + (size_t)col * DH;
  for (int i = 0; i < 16; ++i) {
    int k = i * 64 + lane;
    float wv = wc_[k];
    a0 += wv * e[k];
    a1 += wv * e[DH + k];
    a2 += wv * e[2 * DH + k];
    a3 += wv * e[3 * DH + k];
  }
  #pragma unroll
  for (int msk = 32; msk; msk >>= 1) {
    a0 += __shfl_xor(a0, msk); a1 += __shfl_xor(a1, msk);
    a2 += __shfl_xor(a2, msk); a3 += __shfl_xor(a3, msk);
  }
  if (lane == 0) {
    float bb = bs[col] + addc;
    out[mat * (4 * DH) + 0 * DH + col] = a0 + bb;
    out[mat * (4 * DH) + 1 * DH + col] = a1 + bb;
    out[mat * (4 * DH) + 2 * DH + col] = a2 + bb;
    out[mat * (4 * DH) + 3 * DH + col] = a3 + bb;
  }
}

// ---------------- fused LayerNorm + adaLN modulate -> bf16 ----------------
__global__ __launch_bounds__(256) void ln_mod_kernel(
    const float* __restrict__ x, const float* __restrict__ g, const float* __restrict__ bta,
    const float* __restrict__ sp, const float* __restrict__ off, u16* __restrict__ out) {
  int row = blockIdx.x;
  int b = row >> 10;
  int tid = threadIdx.x;
  int wid = tid >> 6, lane = tid & 63;
  const float4 xv = reinterpret_cast<const float4*>(x + (size_t)row * DH)[tid];
  float s = xv.x + xv.y + xv.z + xv.w;
  float ss = xv.x * xv.x + xv.y * xv.y + xv.z * xv.z + xv.w * xv.w;
  #pragma unroll
  for (int m = 32; m; m >>= 1) { s += __shfl_xor(s, m); ss += __shfl_xor(ss, m); }
  __shared__ float red[8];
  if (lane == 0) { red[wid] = s; red[4 + wid] = ss; }
  __syncthreads();
  s = red[0] + red[1] + red[2] + red[3];
  ss = red[4] + red[5] + red[6] + red[7];
  float mean = s * (1.f / DH);
  float var = ss * (1.f / DH) - mean * mean;
  float rstd = rsqrtf(var + 1e-5f);
  int c = tid * 4;
  const float* spb = sp + b * DH + c;
  const float* offb = off + b * DH + c;
  float y0 = (xv.x - mean) * rstd * g[c + 0] + bta[c + 0];
  float y1 = (xv.y - mean) * rstd * g[c + 1] + bta[c + 1];
  float y2 = (xv.z - mean) * rstd * g[c + 2] + bta[c + 2];
  float y3 = (xv.w - mean) * rstd * g[c + 3] + bta[c + 3];
  ushort4 o;
  o.x = f2bf(spb[0] * y0 + offb[0]);
  o.y = f2bf(spb[1] * y1 + offb[1]);
  o.z = f2bf(spb[2] * y2 + offb[2]);
  o.w = f2bf(spb[3] * y3 + offb[3]);
  reinterpret_cast<ushort4*>(out + (size_t)row * DH)[tid] = o;
}

// ======== 256x128 tile, BK=32, 3-deep rotating pipeline, ONE barrier per K-step ========
enum { EPI_BF16 = 0, EPI_GELU = 1, EPI_PART = 2, EPI_RES = 3 };

template <int EPI>
__global__ __launch_bounds__(512, 2) void gemmT_kernel(
    const u16* __restrict__ A, const u16* __restrict__ W,
    const float* __restrict__ bias, const float* __restrict__ resid,
    void* __restrict__ outp, int N, int K) {
  extern __shared__ u16 lds[];
  u16* Ab = lds;            // [3][256*32] u16 (48 KiB)
  u16* Bb = lds + 24576;    // [3][128*32] u16 (24 KiB)
  int tid = threadIdx.x;
  int wid = tid >> 6, lane = tid & 63;
  int l15 = lane & 15, l4 = lane >> 4;
  int wr = wid >> 2, wc = wid & 3;   // 2M x 4N waves, per-wave 128x32 out

  int nwg = gridDim.x * gridDim.y;
  int lin = blockIdx.y * gridDim.x + blockIdx.x;
  int q8 = nwg >> 3;
  int lin2 = (lin & 7) * q8 + (lin >> 3);
  int bx = lin2 % gridDim.x, by = lin2 / gridDim.x;
  int m0 = by * 256, n0 = bx * 128;
  int k0 = blockIdx.z * 1024;   // KT=32 -> 1024 K per z-slice

  f32x4 acc[8][2] = {};

  const u16* Abase = A + (size_t)m0 * K + k0;
  const u16* Wbase = W + (size_t)n0 * K + k0;
  int i0 = tid, i1 = 512 + tid;
  int r0 = i0 >> 2, c0 = (i0 & 3) ^ ((r0 >> 1) & 3);
  int r1 = i1 >> 2, c1 = (i1 & 3) ^ ((r1 >> 1) & 3);
  int rB = tid >> 2, cB = (tid & 3) ^ ((rB >> 1) & 3);
  size_t gA0 = (size_t)r0 * K + c0 * 8;
  size_t gA1 = (size_t)r1 * K + c1 * 8;
  size_t gB0 = (size_t)rB * K + cB * 8;
  int lbA0 = (wid * 64) * 8;
  int lbA1 = (512 + wid * 64) * 8;

  auto stage = [&](int tt, int bi) {
    int qa = bi * 8192, qb = bi * 4096;
    const u16* Ak = Abase + tt * 32;
    const u16* Wk = Wbase + tt * 32;
    async16(Ak + gA0, &Ab[qa + lbA0]);
    async16(Ak + gA1, &Ab[qa + lbA1]);
    async16(Wk + gB0, &Bb[qb + lbA0]);
  };

  auto compute = [&](int bi) {
    int qa = bi * 8192, qb = bi * 4096;
    bf16x8 af[8], bfr[2];
    #pragma unroll
    for (int m = 0; m < 8; ++m) {
      int row = wr * 128 + m * 16 + l15;
      int ps = l4 ^ ((row >> 1) & 3);
      af[m] = *reinterpret_cast<const bf16x8*>(&Ab[qa + row * 32 + ps * 8]);
    }
    #pragma unroll
    for (int n = 0; n < 2; ++n) {
      int row = wc * 32 + n * 16 + l15;
      int ps = l4 ^ ((row >> 1) & 3);
      bfr[n] = *reinterpret_cast<const bf16x8*>(&Bb[qb + row * 32 + ps * 8]);
    }
    #pragma unroll
    for (int m = 0; m < 8; ++m)
      #pragma unroll
      for (int n = 0; n < 2; ++n)
        acc[m][n] = MFMA16(af[m], bfr[n], acc[m][n]);
  };

  stage(0, 0);
  stage(1, 1);
  for (int tb = 0; tb < 30; tb += 3) {
    VMCNT(3); BAR(); stage(tb + 2, 2); compute(0);
    VMCNT(3); BAR(); stage(tb + 3, 0); compute(1);
    VMCNT(3); BAR(); stage(tb + 4, 1); compute(2);
  }
  VMCNT(3); BAR(); compute(0);   // t=30
  VMCNT(0); BAR(); compute(1);   // t=31

  int M = gridDim.y * 256;
  u16* pout = (u16*)outp + (size_t)blockIdx.z * M * N;   // bf16 partials for split-K
  #pragma unroll
  for (int n = 0; n < 2; ++n) {
    int col = n0 + wc * 32 + n * 16 + l15;
    float bv = (EPI == EPI_PART) ? 0.f : bias[col];
    #pragma unroll
    for (int m = 0; m < 8; ++m) {
      #pragma unroll
      for (int r = 0; r < 4; ++r) {
        int rowg = m0 + wr * 128 + m * 16 + l4 * 4 + r;
        float v = acc[m][n][r] + bv;
        if (EPI == EPI_GELU) {
          v = 0.5f * v * (1.f + erff(v * 0.70710678118f));
          ((u16*)outp)[(size_t)rowg * N + col] = f2bf(v);
        } else if (EPI == EPI_BF16) {
          ((u16*)outp)[(size_t)rowg * N + col] = f2bf(v);
        } else if (EPI == EPI_RES) {
          ((float*)outp)[(size_t)rowg * N + col] = v + resid[(size_t)rowg * N + col];
        } else {
          pout[(size_t)rowg * N + col] = f2bf(v);
        }
      }
    }
  }
}

// ---------------- split-K reduce (bf16 partials) + te passthrough ----------------
__global__ __launch_bounds__(256) void reduce4_kernel(
    const u16* __restrict__ part, const float* __restrict__ x2,
    const float* __restrict__ bias, const float* __restrict__ te,
    float* __restrict__ out) {
  size_t i = (size_t)blockIdx.x * 256 + threadIdx.x;
  const size_t MN = (size_t)4096 * 1024;
  float4 xr = reinterpret_cast<const float4*>(x2)[i];
  int col = (int)((i * 4) & 1023);
  float4 bv = *reinterpret_cast<const float4*>(&bias[col]);
  float a0 = xr.x + bv.x, a1 = xr.y + bv.y, a2 = xr.z + bv.z, a3 = xr.w + bv.w;
  #pragma unroll
  for (int p = 0; p < 4; ++p) {
    ushort4 u = reinterpret_cast<const ushort4*>(part + p * MN)[i];
    a0 += bf2f(u.x); a1 += bf2f(u.y); a2 += bf2f(u.z); a3 += bf2f(u.w);
  }
  float4 o; o.x = a0; o.y = a1; o.z = a2; o.w = a3;
  reinterpret_cast<float4*>(out)[i] = o;
  if (blockIdx.x < 16) {
    int ii = blockIdx.x * 256 + threadIdx.x;
    out[4096 * 1024 + ii] = te[ii];
  }
}

// ---------------- V pre-transpose: qkvb V-part -> vT[bh][d=64][n=1024] ----------------
__global__ __launch_bounds__(256) void vt_kernel(const u16* __restrict__ qkvb,
                                                 u16* __restrict__ vT) {
  __shared__ u16 L[64 * 66];
  int bh = blockIdx.y;
  int b = bh >> 4, h = bh & 15;
  int nt = blockIdx.x;
  int t = threadIdx.x;
  const u16* src = qkvb + ((size_t)b * 1024 + nt * 64) * 3072 + 2048 + h * 64;
  int j = t >> 3, s = t & 7;
  bf16x8 r0 = *reinterpret_cast<const bf16x8*>(src + (size_t)j * 3072 + s * 8);
  bf16x8 r1 = *reinterpret_cast<const bf16x8*>(src + (size_t)(j + 32) * 3072 + s * 8);
  #pragma unroll
  for (int e = 0; e < 8; ++e) {
    L[(s * 8 + e) * 66 + j] = r0[e];
    L[(s * 8 + e) * 66 + j + 32] = r1[e];
  }
  __syncthreads();
  int d = t & 63, cp = t >> 6;
  u16* dst = vT + ((size_t)bh * 64 + d) * 1024 + nt * 64;
  #pragma unroll
  for (int half = 0; half < 2; ++half) {
    int cs = cp + half * 4;
    bf16x8 o;
    #pragma unroll
    for (int c = 0; c < 8; ++c) o[c] = L[d * 66 + cs * 8 + c];
    *reinterpret_cast<bf16x8*>(dst + cs * 8) = o;
  }
}

// ---------------- flash attention: swapped QK^T, 2 q-groups per wave (K/V read reuse) ----------------
// Block = 128 q-rows (4 waves x 32). kf/vf LDS reads shared across the two q-groups:
// 8 K-reads : 16 QK-MFMA, 8 V-reads : 16 PV-MFMA (was 1:1).
__global__ __launch_bounds__(256, 2) void attn_kernel(
    const u16* __restrict__ qkv, const u16* __restrict__ vT, u16* __restrict__ out) {
  __shared__ __align__(16) u16 Ks[2][4096];
  __shared__ __align__(16) u16 Vs[2][4096];
  int tid = threadIdx.x, wid = tid >> 6, lane = tid & 63;
  int l15 = lane & 15, l4 = lane >> 4;
  // grid = 512: qt(3 bits 3..5), bh = (L&7) | ((L>>6)<<3); all 8 q-tiles of (b,h) share L%8
  int L = blockIdx.y * gridDim.x + blockIdx.x;
  int qt = (L >> 3) & 7;
  int bh = (L & 7) | ((L >> 6) << 3);
  int b = bh >> 4, h = bh & 15;
  const size_t SN = 3 * DH;
  const u16* qb = qkv + (size_t)b * NN * SN + h * HD;
  const u16* kb = qb + DH;
  const u16* vtb = vT + (size_t)bh * 64 * 1024;

  bf16x8 qf0[2], qf1[2];
  {
    int qr0 = qt * 128 + wid * 32 + l15;
    int qr1 = qr0 + 16;
    #pragma unroll
    for (int ks = 0; ks < 2; ++ks) {
      qf0[ks] = *reinterpret_cast<const bf16x8*>(qb + (size_t)qr0 * SN + ks * 32 + l4 * 8);
      qf1[ks] = *reinterpret_cast<const bf16x8*>(qb + (size_t)qr1 * SN + ks * 32 + l4 * 8);
    }
  }

  float m0_ = -1e30f, l0_ = 0.f, m1_ = -1e30f, l1_ = 0.f;
  f32x4 o0_[4] = {}, o1_[4] = {};

  int laA = ((l4 * 2) & 3) * 16 + l15;
  int laB = ((l4 * 2 + 1) & 3) * 16 + l15;
  bool nbhi = (l4 >> 1) != 0;

  int iA = tid, iB = 256 + tid;
  int jA = iA >> 3, sA = iA & 7, gsA = sA ^ (jA & 7);
  int jB = iB >> 3, sB = iB & 7, gsB = sB ^ (jB & 7);

  auto stageKV = [&](int bufn, int t) {
    const u16* kt = kb + (size_t)t * 64 * SN;
    async16(kt + (size_t)jA * SN + gsA * 8, &Ks[bufn][iA * 8]);
    async16(kt + (size_t)jB * SN + gsB * 8, &Ks[bufn][iB * 8]);
    const u16* vt = vtb + (size_t)t * 64;
    async16(vt + (size_t)jA * 1024 + gsA * 8, &Vs[bufn][iA * 8]);
    async16(vt + (size_t)jB * 1024 + gsB * 8, &Vs[bufn][iB * 8]);
  };

  stageKV(0, 0);
  __syncthreads();

  int buf = 0;
  for (int t = 0; t < 16; ++t) {
    if (t < 15) stageKV(buf ^ 1, t + 1);

    // ---- QK^T swapped, both q-groups share each kf read
    f32x4 sa0[4], sa1[4];
    #pragma unroll
    for (int nb = 0; nb < 4; ++nb) {
      f32x4 s0 = {}, s1 = {};
      #pragma unroll
      for (int ks = 0; ks < 2; ++ks) {
        int j = nb * 16 + l15;
        int ps = (ks * 4 + l4) ^ (j & 7);
        bf16x8 kf = *reinterpret_cast<const bf16x8*>(&Ks[buf][j * 64 + ps * 8]);
        s0 = MFMA16(kf, qf0[ks], s0);
        s1 = MFMA16(kf, qf1[ks], s1);
      }
      sa0[nb] = s0 * 0.125f;
      sa1[nb] = s1 * 0.125f;
    }

    // ---- row max per group
    float pm0 = sa0[0][0], pm1 = sa1[0][0];
    #pragma unroll
    for (int nb = 0; nb < 4; ++nb)
      #pragma unroll
      for (int r = 0; r < 4; ++r) {
        if (nb || r) { pm0 = fmaxf(pm0, sa0[nb][r]); pm1 = fmaxf(pm1, sa1[nb][r]); }
      }
    pm0 = fmaxf(pm0, __shfl_xor(pm0, 16)); pm0 = fmaxf(pm0, __shfl_xor(pm0, 32));
    pm1 = fmaxf(pm1, __shfl_xor(pm1, 16)); pm1 = fmaxf(pm1, __shfl_xor(pm1, 32));

    // ---- defer-max (THR=8), combined trigger, per-group rescale
    if (!__all(fmaxf(pm0 - m0_, pm1 - m1_) <= 8.f)) {
      float mn0 = fmaxf(m0_, pm0), mn1 = fmaxf(m1_, pm1);
      float cr0 = __expf(m0_ - mn0), cr1 = __expf(m1_ - mn1);
      m0_ = mn0; m1_ = mn1;
      l0_ *= cr0; l1_ *= cr1;
      #pragma unroll
      for (int r = 0; r < 4; ++r) {
        float c0 = __shfl(cr0, l4 * 4 + r);
        float c1 = __shfl(cr1, l4 * 4 + r);
        #pragma unroll
        for (int nd = 0; nd < 4; ++nd) { o0_[nd][r] *= c0; o1_[nd][r] *= c1; }
      }
    }

    // ---- exp + sum + pack (per group)
    float ts0 = 0.f, ts1 = 0.f;
    u32 pk0[4][2], pk1[4][2];
    #pragma unroll
    for (int nb = 0; nb < 4; ++nb) {
      float a0 = __expf(sa0[nb][0] - m0_), a1 = __expf(sa0[nb][1] - m0_);
      float a2 = __expf(sa0[nb][2] - m0_), a3 = __expf(sa0[nb][3] - m0_);
      ts0 += (a0 + a1) + (a2 + a3);
      pk0[nb][0] = (u32)f2bf(a0) | ((u32)f2bf(a1) << 16);
      pk0[nb][1] = (u32)f2bf(a2) | ((u32)f2bf(a3) << 16);
      float b0 = __expf(sa1[nb][0] - m1_), b1 = __expf(sa1[nb][1] - m1_);
      float b2 = __expf(sa1[nb][2] - m1_), b3 = __expf(sa1[nb][3] - m1_);
      ts1 += (b0 + b1) + (b2 + b3);
      pk1[nb][0] = (u32)f2bf(b0) | ((u32)f2bf(b1) << 16);
      pk1[nb][1] = (u32)f2bf(b2) | ((u32)f2bf(b3) << 16);
    }
    ts0 += __shfl_xor(ts0, 16); ts0 += __shfl_xor(ts0, 32); l0_ += ts0;
    ts1 += __shfl_xor(ts1, 16); ts1 += __shfl_xor(ts1, 32); l1_ += ts1;

    // ---- PV: both groups share each vf read
    __builtin_amdgcn_s_setprio(1);
    #pragma unroll
    for (int ks = 0; ks < 2; ++ks) {
      int nlo = ks * 2, nhi = ks * 2 + 1;
      u32x4 w0, w1;
      {
        u32 a00 = __shfl((int)pk0[nlo][0], laA), a01 = __shfl((int)pk0[nlo][1], laA);
        u32 a10 = __shfl((int)pk0[nhi][0], laA), a11 = __shfl((int)pk0[nhi][1], laA);
        u32 b00 = __shfl((int)pk0[nlo][0], laB), b01 = __shfl((int)pk0[nlo][1], laB);
        u32 b10 = __shfl((int)pk0[nhi][0], laB), b11 = __shfl((int)pk0[nhi][1], laB);
        w0[0] = nbhi ? a10 : a00; w0[1] = nbhi ? a11 : a01;
        w0[2] = nbhi ? b10 : b00; w0[3] = nbhi ? b11 : b01;
      }
      {
        u32 a00 = __shfl((int)pk1[nlo][0], laA), a01 = __shfl((int)pk1[nlo][1], laA);
        u32 a10 = __shfl((int)pk1[nhi][0], laA), a11 = __shfl((int)pk1[nhi][1], laA);
        u32 b00 = __shfl((int)pk1[nlo][0], laB), b01 = __shfl((int)pk1[nlo][1], laB);
        u32 b10 = __shfl((int)pk1[nhi][0], laB), b11 = __shfl((int)pk1[nhi][1], laB);
        w1[0] = nbhi ? a10 : a00; w1[1] = nbhi ? a11 : a01;
        w1[2] = nbhi ? b10 : b00; w1[3] = nbhi ? b11 : b01;
      }
      bf16x8 pa0 = __builtin_bit_cast(bf16x8, w0);
      bf16x8 pa1 = __builtin_bit_cast(bf16x8, w1);
      #pragma unroll
      for (int nd = 0; nd < 4; ++nd) {
        int d = nd * 16 + l15;
        int psv = (ks * 4 + l4) ^ (d & 7);
        bf16x8 vf = *reinterpret_cast<const bf16x8*>(&Vs[buf][d * 64 + psv * 8]);
        o0_[nd] = MFMA16(pa0, vf, o0_[nd]);
        o1_[nd] = MFMA16(pa1, vf, o1_[nd]);
      }
    }
    __builtin_amdgcn_s_setprio(0);

    if (t < 15) __syncthreads();
    buf ^= 1;
  }

  u16* ob = out + (size_t)b * NN * DH + h * HD;
  #pragma unroll
  for (int r = 0; r < 4; ++r) {
    float inv0 = 1.f / __shfl(l0_, l4 * 4 + r);
    float inv1 = 1.f / __shfl(l1_, l4 * 4 + r);
    int q0 = qt * 128 + wid * 32 + l4 * 4 + r;
    int q1 = q0 + 16;
    #pragma unroll
    for (int nd = 0; nd < 4; ++nd) {
      ob[(size_t)q0 * DH + nd * 16 + l15] = f2bf(o0_[nd][r] * inv0);
      ob[(size_t)q1 * DH + nd * 16 + l15] = f2bf(o1_[nd][r] * inv1);
    }
  }
}

extern "C" void kernel_launch(void* const* d_in, const int* in_sizes, int n_in,
                              void* d_out, int out_size, void* d_ws, size_t ws_size,
                              hipStream_t stream) {
  (void)in_sizes; (void)n_in; (void)out_size; (void)ws_size;
  const float* x      = (const float*)d_in[0];
  const float* te     = (const float*)d_in[1];
  const float* ln1_g  = (const float*)d_in[2];
  const float* ln1_b  = (const float*)d_in[3];
  const float* s1_w   = (const float*)d_in[4];
  const float* s1_b   = (const float*)d_in[5];
  const float* o1_w   = (const float*)d_in[6];
  const float* o1_b   = (const float*)d_in[7];
  const float* qkv_w  = (const float*)d_in[8];
  const float* qkv_b  = (const float*)d_in[9];
  const float* proj_w = (const float*)d_in[10];
  const float* proj_b = (const float*)d_in[11];
  const float* ln2_g  = (const float*)d_in[12];
  const float* ln2_b  = (const float*)d_in[13];
  const float* s2_w   = (const float*)d_in[14];
  const float* s2_b   = (const float*)d_in[15];
  const float* o2_w   = (const float*)d_in[16];
  const float* o2_b   = (const float*)d_in[17];
  const float* up_w   = (const float*)d_in[18];
  const float* up_b   = (const float*)d_in[19];
  const float* down_w = (const float*)d_in[20];
  const float* down_b = (const float*)d_in[21];

  char* ws = (char*)d_ws;
  size_t off = 0;
  auto alloc = [&](size_t bytes) { void* p = ws + off; off += (bytes + 255) & ~255ull; return p; };
  u16*   wq   = (u16*)  alloc((size_t)3072 * 1024 * 2);
  u16*   wp   = (u16*)  alloc((size_t)1024 * 1024 * 2);
  u16*   wu   = (u16*)  alloc((size_t)4096 * 1024 * 2);
  u16*   h1   = (u16*)  alloc((size_t)4096 * 1024 * 2);
  u16*   qkvb = (u16*)  alloc((size_t)4096 * 3072 * 2);
  u16*   att  = (u16*)  alloc((size_t)4096 * 1024 * 2);
  u16*   h2   = (u16*)  alloc((size_t)4096 * 1024 * 2);
  u16*   wd   = (u16*)  alloc((size_t)1024 * 4096 * 2);
  float* x2   = (float*)alloc((size_t)4096 * 1024 * 4);
  u16*   upb  = (u16*)  alloc((size_t)4096 * 4096 * 2);
  float* ada  = (float*)alloc((size_t)4 * 4 * 1024 * 4);
  float* sp1 = ada, *off1 = ada + 4096, *sp2 = ada + 8192, *off2 = ada + 12288;
  u16*   part = wq;
  u16*   vT   = h1;

  cvt_all_kernel<<<12288, 256, 0, stream>>>(qkv_w, proj_w, up_w, down_w, wq, wp, wu, wd);
  adaln_kernel<<<dim3(256, 4), 256, 0, stream>>>(te, s1_w, s1_b, o1_w, o1_b, s2_w, s2_b, o2_w, o2_b, ada);
  ln_mod_kernel<<<4096, 256, 0, stream>>>(x, ln1_g, ln1_b, sp1, off1, h1);
  gemmT_kernel<EPI_BF16><<<dim3(24, 16, 1), 512, 73728, stream>>>(h1, wq, qkv_b, nullptr, qkvb, 3072, 1024);
  vt_kernel<<<dim3(16, 64), 256, 0, stream>>>(qkvb, vT);
  attn_kernel<<<dim3(8, 64), 256, 0, stream>>>(qkvb, vT, att);
  gemmT_kernel<EPI_RES><<<dim3(8, 16, 1), 512, 73728, stream>>>(att, wp, proj_b, x, x2, 1024, 1024);
  ln_mod_kernel<<<4096, 256, 0, stream>>>(x2, ln2_g, ln2_b, sp2, off2, h2);
  gemmT_kernel<EPI_GELU><<<dim3(32, 16, 1), 512, 73728, stream>>>(h2, wu, up_b, nullptr, upb, 4096, 1024);
  gemmT_kernel<EPI_PART><<<dim3(8, 16, 4), 512, 73728, stream>>>(upb, wd, nullptr, nullptr, part, 1024, 4096);
  reduce4_kernel<<<4096, 256, 0, stream>>>(part, x2, down_b, te, (float*)d_out);
}

// Round 17
// 241.585 us; speedup vs baseline: 1.0064x; 1.0064x over previous
//
#include <hip/hip_runtime.h>
#include <hip/hip_bf16.h>
#include <math.h>

#define DH 1024
#define BB 4
#define NN 1024
#define NH 16
#define HD 64

typedef __attribute__((ext_vector_type(8))) short bf16x8;
typedef __attribute__((ext_vector_type(4))) float f32x4;
typedef __attribute__((ext_vector_type(4))) unsigned int u32x4;
typedef unsigned short u16;
typedef unsigned int u32;

static __device__ __forceinline__ u16 f2bf(float f) {
  __hip_bfloat16 h = __float2bfloat16(f);
  return *reinterpret_cast<u16*>(&h);
}
static __device__ __forceinline__ float bf2f(u16 x) {
  return __uint_as_float((unsigned)x << 16);
}

#define MFMA16(a, b, c) __builtin_amdgcn_mfma_f32_16x16x32_bf16(a, b, c, 0, 0, 0)
#define VMCNT(n) asm volatile("s_waitcnt vmcnt(" #n ")" ::: "memory")
#define MEMFENCE asm volatile("" ::: "memory")
#define BAR() do { __builtin_amdgcn_s_barrier(); MEMFENCE; } while (0)

static __device__ __forceinline__ void async16(const void* g, void* l) {
  __builtin_amdgcn_global_load_lds(
      (const __attribute__((address_space(1))) void*)g,
      (__attribute__((address_space(3))) void*)l, 16, 0, 0);
}

// ---------------- fused weight fp32 -> bf16 (all 4 weights, 1 launch) ----------------
__global__ void cvt_all_kernel(const float* __restrict__ wq, const float* __restrict__ wp,
                               const float* __restrict__ wu, const float* __restrict__ wd,
                               u16* __restrict__ oq, u16* __restrict__ op,
                               u16* __restrict__ ou, u16* __restrict__ od) {
  int i = blockIdx.x * 256 + threadIdx.x;  // float4 index, total 3145728
  const float* src; u16* dst; int off;
  if (i < 786432)            { src = wq; dst = oq; off = i; }
  else if (i < 1048576)      { src = wp; dst = op; off = i - 786432; }
  else if (i < 2097152)      { src = wu; dst = ou; off = i - 1048576; }
  else                       { src = wd; dst = od; off = i - 2097152; }
  float4 v = reinterpret_cast<const float4*>(src)[off];
  ushort4 o;
  o.x = f2bf(v.x); o.y = f2bf(v.y); o.z = f2bf(v.z); o.w = f2bf(v.w);
  reinterpret_cast<ushort4*>(dst)[off] = o;
}

// ---------------- adaLN small linears (4 rows of time_emb) ----------------
__global__ __launch_bounds__(256) void adaln_kernel(
    const float* __restrict__ e,
    const float* __restrict__ w_s1, const float* __restrict__ b_s1,
    const float* __restrict__ w_o1, const float* __restrict__ b_o1,
    const float* __restrict__ w_s2, const float* __restrict__ b_s2,
    const float* __restrict__ w_o2, const float* __restrict__ b_o2,
    float* __restrict__ out) {
  int tid = threadIdx.x, wid = tid >> 6, lane = tid & 63;
  int mat = blockIdx.y;
  const float* w; const float* bs; float addc;
  if (mat == 0)      { w = w_s1; bs = b_s1; addc = 1.f; }
  else if (mat == 1) { w = w_o1; bs = b_o1; addc = 0.f; }
  else if (mat == 2) { w = w_s2; bs = b_s2; addc = 1.f; }
  else               { w = w_o2; bs = b_o2; addc = 0.f; }
  int col = blockIdx.x * 4 + wid;
  float a0 = 0.f, a1 = 0.f, a2 = 0.f, a3 = 0.f;
  const float* wc_ = w + (size_t)col * DH;
  for (int i = 0; i < 16; ++i) {
    int k = i * 64 + lane;
    float wv = wc_[k];
    a0 += wv * e[k];
    a1 += wv * e[DH + k];
    a2 += wv * e[2 * DH + k];
    a3 += wv * e[3 * DH + k];
  }
  #pragma unroll
  for (int msk = 32; msk; msk >>= 1) {
    a0 += __shfl_xor(a0, msk); a1 += __shfl_xor(a1, msk);
    a2 += __shfl_xor(a2, msk); a3 += __shfl_xor(a3, msk);
  }
  if (lane == 0) {
    float bb = bs[col] + addc;
    out[mat * (4 * DH) + 0 * DH + col] = a0 + bb;
    out[mat * (4 * DH) + 1 * DH + col] = a1 + bb;
    out[mat * (4 * DH) + 2 * DH + col] = a2 + bb;
    out[mat * (4 * DH) + 3 * DH + col] = a3 + bb;
  }
}

// ---------------- fused LayerNorm + adaLN modulate -> bf16 ----------------
__global__ __launch_bounds__(256) void ln_mod_kernel(
    const float* __restrict__ x, const float* __restrict__ g, const float* __restrict__ bta,
    const float* __restrict__ sp, const float* __restrict__ off, u16* __restrict__ out) {
  int row = blockIdx.x;
  int b = row >> 10;
  int tid = threadIdx.x;
  int wid = tid >> 6, lane = tid & 63;
  const float4 xv = reinterpret_cast<const float4*>(x + (size_t)row * DH)[tid];
  float s = xv.x + xv.y + xv.z + xv.w;
  float ss = xv.x * xv.x + xv.y * xv.y + xv.z * xv.z + xv.w * xv.w;
  #pragma unroll
  for (int m = 32; m; m >>= 1) { s += __shfl_xor(s, m); ss += __shfl_xor(ss, m); }
  __shared__ float red[8];
  if (lane == 0) { red[wid] = s; red[4 + wid] = ss; }
  __syncthreads();
  s = red[0] + red[1] + red[2] + red[3];
  ss = red[4] + red[5] + red[6] + red[7];
  float mean = s * (1.f / DH);
  float var = ss * (1.f / DH) - mean * mean;
  float rstd = rsqrtf(var + 1e-5f);
  int c = tid * 4;
  const float* spb = sp + b * DH + c;
  const float* offb = off + b * DH + c;
  float y0 = (xv.x - mean) * rstd * g[c + 0] + bta[c + 0];
  float y1 = (xv.y - mean) * rstd * g[c + 1] + bta[c + 1];
  float y2 = (xv.z - mean) * rstd * g[c + 2] + bta[c + 2];
  float y3 = (xv.w - mean) * rstd * g[c + 3] + bta[c + 3];
  ushort4 o;
  o.x = f2bf(spb[0] * y0 + offb[0]);
  o.y = f2bf(spb[1] * y1 + offb[1]);
  o.z = f2bf(spb[2] * y2 + offb[2]);
  o.w = f2bf(spb[3] * y3 + offb[3]);
  reinterpret_cast<ushort4*>(out + (size_t)row * DH)[tid] = o;
}

// ======== 256x128 tile, BK=32, 3-deep rotating pipeline, ONE barrier per K-step ========
// Round-13/15 measured-best config (128x32 wave tiles). KT hard-coded 32.
enum { EPI_BF16 = 0, EPI_GELU = 1, EPI_PART = 2, EPI_RES = 3 };

template <int EPI>
__global__ __launch_bounds__(512, 2) void gemmT_kernel(
    const u16* __restrict__ A, const u16* __restrict__ W,
    const float* __restrict__ bias, const float* __restrict__ resid,
    void* __restrict__ outp, int N, int K) {
  extern __shared__ u16 lds[];
  u16* Ab = lds;            // [3][256*32] u16 (48 KiB)
  u16* Bb = lds + 24576;    // [3][128*32] u16 (24 KiB)
  int tid = threadIdx.x;
  int wid = tid >> 6, lane = tid & 63;
  int l15 = lane & 15, l4 = lane >> 4;
  int wr = wid >> 2, wc = wid & 3;   // 2M x 4N waves, per-wave 128x32 out

  int nwg = gridDim.x * gridDim.y;
  int lin = blockIdx.y * gridDim.x + blockIdx.x;
  int q8 = nwg >> 3;
  int lin2 = (lin & 7) * q8 + (lin >> 3);
  int bx = lin2 % gridDim.x, by = lin2 / gridDim.x;
  int m0 = by * 256, n0 = bx * 128;
  int k0 = blockIdx.z * 1024;   // KT=32 -> 1024 K per z-slice

  f32x4 acc[8][2] = {};

  const u16* Abase = A + (size_t)m0 * K + k0;
  const u16* Wbase = W + (size_t)n0 * K + k0;
  int i0 = tid, i1 = 512 + tid;
  int r0 = i0 >> 2, c0 = (i0 & 3) ^ ((r0 >> 1) & 3);
  int r1 = i1 >> 2, c1 = (i1 & 3) ^ ((r1 >> 1) & 3);
  int rB = tid >> 2, cB = (tid & 3) ^ ((rB >> 1) & 3);
  size_t gA0 = (size_t)r0 * K + c0 * 8;
  size_t gA1 = (size_t)r1 * K + c1 * 8;
  size_t gB0 = (size_t)rB * K + cB * 8;
  int lbA0 = (wid * 64) * 8;
  int lbA1 = (512 + wid * 64) * 8;

  auto stage = [&](int tt, int bi) {
    int qa = bi * 8192, qb = bi * 4096;
    const u16* Ak = Abase + tt * 32;
    const u16* Wk = Wbase + tt * 32;
    async16(Ak + gA0, &Ab[qa + lbA0]);
    async16(Ak + gA1, &Ab[qa + lbA1]);
    async16(Wk + gB0, &Bb[qb + lbA0]);
  };

  auto compute = [&](int bi) {
    int qa = bi * 8192, qb = bi * 4096;
    bf16x8 af[8], bfr[2];
    #pragma unroll
    for (int m = 0; m < 8; ++m) {
      int row = wr * 128 + m * 16 + l15;
      int ps = l4 ^ ((row >> 1) & 3);
      af[m] = *reinterpret_cast<const bf16x8*>(&Ab[qa + row * 32 + ps * 8]);
    }
    #pragma unroll
    for (int n = 0; n < 2; ++n) {
      int row = wc * 32 + n * 16 + l15;
      int ps = l4 ^ ((row >> 1) & 3);
      bfr[n] = *reinterpret_cast<const bf16x8*>(&Bb[qb + row * 32 + ps * 8]);
    }
    #pragma unroll
    for (int m = 0; m < 8; ++m)
      #pragma unroll
      for (int n = 0; n < 2; ++n)
        acc[m][n] = MFMA16(af[m], bfr[n], acc[m][n]);
  };

  stage(0, 0);
  stage(1, 1);
  for (int tb = 0; tb < 30; tb += 3) {
    VMCNT(3); BAR(); stage(tb + 2, 2); compute(0);
    VMCNT(3); BAR(); stage(tb + 3, 0); compute(1);
    VMCNT(3); BAR(); stage(tb + 4, 1); compute(2);
  }
  VMCNT(3); BAR(); compute(0);   // t=30
  VMCNT(0); BAR(); compute(1);   // t=31

  int M = gridDim.y * 256;
  u16* pout = (u16*)outp + (size_t)blockIdx.z * M * N;   // bf16 partials for split-K
  #pragma unroll
  for (int n = 0; n < 2; ++n) {
    int col = n0 + wc * 32 + n * 16 + l15;
    float bv = (EPI == EPI_PART) ? 0.f : bias[col];
    #pragma unroll
    for (int m = 0; m < 8; ++m) {
      #pragma unroll
      for (int r = 0; r < 4; ++r) {
        int rowg = m0 + wr * 128 + m * 16 + l4 * 4 + r;
        float v = acc[m][n][r] + bv;
        if (EPI == EPI_GELU) {
          v = 0.5f * v * (1.f + erff(v * 0.70710678118f));
          ((u16*)outp)[(size_t)rowg * N + col] = f2bf(v);
        } else if (EPI == EPI_BF16) {
          ((u16*)outp)[(size_t)rowg * N + col] = f2bf(v);
        } else if (EPI == EPI_RES) {
          ((float*)outp)[(size_t)rowg * N + col] = v + resid[(size_t)rowg * N + col];
        } else {
          pout[(size_t)rowg * N + col] = f2bf(v);
        }
      }
    }
  }
}

// ---------------- split-K reduce (bf16 partials) + te passthrough ----------------
__global__ __launch_bounds__(256) void reduce4_kernel(
    const u16* __restrict__ part, const float* __restrict__ x2,
    const float* __restrict__ bias, const float* __restrict__ te,
    float* __restrict__ out) {
  size_t i = (size_t)blockIdx.x * 256 + threadIdx.x;
  const size_t MN = (size_t)4096 * 1024;
  float4 xr = reinterpret_cast<const float4*>(x2)[i];
  int col = (int)((i * 4) & 1023);
  float4 bv = *reinterpret_cast<const float4*>(&bias[col]);
  float a0 = xr.x + bv.x, a1 = xr.y + bv.y, a2 = xr.z + bv.z, a3 = xr.w + bv.w;
  #pragma unroll
  for (int p = 0; p < 4; ++p) {
    ushort4 u = reinterpret_cast<const ushort4*>(part + p * MN)[i];
    a0 += bf2f(u.x); a1 += bf2f(u.y); a2 += bf2f(u.z); a3 += bf2f(u.w);
  }
  float4 o; o.x = a0; o.y = a1; o.z = a2; o.w = a3;
  reinterpret_cast<float4*>(out)[i] = o;
  if (blockIdx.x < 16) {
    int ii = blockIdx.x * 256 + threadIdx.x;
    out[4096 * 1024 + ii] = te[ii];
  }
}

// ---------------- V pre-transpose: qkvb V-part -> vT[bh][d=64][n=1024] ----------------
__global__ __launch_bounds__(256) void vt_kernel(const u16* __restrict__ qkvb,
                                                 u16* __restrict__ vT) {
  __shared__ u16 L[64 * 66];
  int bh = blockIdx.y;
  int b = bh >> 4, h = bh & 15;
  int nt = blockIdx.x;
  int t = threadIdx.x;
  const u16* src = qkvb + ((size_t)b * 1024 + nt * 64) * 3072 + 2048 + h * 64;
  int j = t >> 3, s = t & 7;
  bf16x8 r0 = *reinterpret_cast<const bf16x8*>(src + (size_t)j * 3072 + s * 8);
  bf16x8 r1 = *reinterpret_cast<const bf16x8*>(src + (size_t)(j + 32) * 3072 + s * 8);
  #pragma unroll
  for (int e = 0; e < 8; ++e) {
    L[(s * 8 + e) * 66 + j] = r0[e];
    L[(s * 8 + e) * 66 + j + 32] = r1[e];
  }
  __syncthreads();
  int d = t & 63, cp = t >> 6;
  u16* dst = vT + ((size_t)bh * 64 + d) * 1024 + nt * 64;
  #pragma unroll
  for (int half = 0; half < 2; ++half) {
    int cs = cp + half * 4;
    bf16x8 o;
    #pragma unroll
    for (int c = 0; c < 8; ++c) o[c] = L[d * 66 + cs * 8 + c];
    *reinterpret_cast<bf16x8*>(dst + cs * 8) = o;
  }
}

// ---------------- flash attention: swapped QK^T, fully in-register softmax/P ----------------
// Round-15 measured-best version.
__global__ __launch_bounds__(256, 4) void attn_kernel(
    const u16* __restrict__ qkv, const u16* __restrict__ vT, u16* __restrict__ out) {
  __shared__ __align__(16) u16 Ks[2][4096];
  __shared__ __align__(16) u16 Vs[2][4096];
  int tid = threadIdx.x, wid = tid >> 6, lane = tid & 63;
  int l15 = lane & 15, l4 = lane >> 4;
  int L = blockIdx.y * gridDim.x + blockIdx.x;
  int qt = (L >> 3) & 15;
  int bh = (L & 7) | ((L >> 7) << 3);
  int b = bh >> 4, h = bh & 15;
  const size_t SN = 3 * DH;
  const u16* qb = qkv + (size_t)b * NN * SN + h * HD;
  const u16* kb = qb + DH;
  const u16* vtb = vT + (size_t)bh * 64 * 1024;

  int qrow = qt * 64 + wid * 16 + l15;
  bf16x8 qf[2];
  #pragma unroll
  for (int ks = 0; ks < 2; ++ks)
    qf[ks] = *reinterpret_cast<const bf16x8*>(qb + (size_t)qrow * SN + ks * 32 + l4 * 8);

  float m_ = -1e30f, l_ = 0.f;
  f32x4 o_[4] = {};

  int laA = ((l4 * 2) & 3) * 16 + l15;
  int laB = ((l4 * 2 + 1) & 3) * 16 + l15;
  bool nbhi = (l4 >> 1) != 0;

  int iA = tid, iB = 256 + tid;
  int jA = iA >> 3, sA = iA & 7, gsA = sA ^ (jA & 7);
  int jB = iB >> 3, sB = iB & 7, gsB = sB ^ (jB & 7);

  auto stageKV = [&](int bufn, int t) {
    const u16* kt = kb + (size_t)t * 64 * SN;
    async16(kt + (size_t)jA * SN + gsA * 8, &Ks[bufn][iA * 8]);
    async16(kt + (size_t)jB * SN + gsB * 8, &Ks[bufn][iB * 8]);
    const u16* vt = vtb + (size_t)t * 64;
    async16(vt + (size_t)jA * 1024 + gsA * 8, &Vs[bufn][iA * 8]);
    async16(vt + (size_t)jB * 1024 + gsB * 8, &Vs[bufn][iB * 8]);
  };

  stageKV(0, 0);
  __syncthreads();

  int buf = 0;
  for (int t = 0; t < 16; ++t) {
    if (t < 15) stageKV(buf ^ 1, t + 1);

    f32x4 sa[4];
    #pragma unroll
    for (int nb = 0; nb < 4; ++nb) {
      f32x4 s = {};
      #pragma unroll
      for (int ks = 0; ks < 2; ++ks) {
        int j = nb * 16 + l15;
        int ps = (ks * 4 + l4) ^ (j & 7);
        bf16x8 kf = *reinterpret_cast<const bf16x8*>(&Ks[buf][j * 64 + ps * 8]);
        s = MFMA16(kf, qf[ks], s);
      }
      sa[nb] = s * 0.125f;
    }

    float pm = sa[0][0];
    #pragma unroll
    for (int nb = 0; nb < 4; ++nb)
      #pragma unroll
      for (int r = 0; r < 4; ++r)
        if (nb || r) pm = fmaxf(pm, sa[nb][r]);
    pm = fmaxf(pm, __shfl_xor(pm, 16));
    pm = fmaxf(pm, __shfl_xor(pm, 32));

    if (!__all(pm - m_ <= 8.f)) {
      float mn = fmaxf(m_, pm);
      float corr = __expf(m_ - mn);
      m_ = mn;
      l_ *= corr;
      float c0 = __shfl(corr, l4 * 4 + 0);
      float c1 = __shfl(corr, l4 * 4 + 1);
      float c2 = __shfl(corr, l4 * 4 + 2);
      float c3 = __shfl(corr, l4 * 4 + 3);
      #pragma unroll
      for (int nd = 0; nd < 4; ++nd) {
        o_[nd][0] *= c0; o_[nd][1] *= c1; o_[nd][2] *= c2; o_[nd][3] *= c3;
      }
    }

    float ts = 0.f;
    u32 pk[4][2];
    #pragma unroll
    for (int nb = 0; nb < 4; ++nb) {
      float p0 = __expf(sa[nb][0] - m_);
      float p1 = __expf(sa[nb][1] - m_);
      float p2 = __expf(sa[nb][2] - m_);
      float p3 = __expf(sa[nb][3] - m_);
      ts += (p0 + p1) + (p2 + p3);
      pk[nb][0] = (u32)f2bf(p0) | ((u32)f2bf(p1) << 16);
      pk[nb][1] = (u32)f2bf(p2) | ((u32)f2bf(p3) << 16);
    }
    ts += __shfl_xor(ts, 16);
    ts += __shfl_xor(ts, 32);
    l_ += ts;

    __builtin_amdgcn_s_setprio(1);
    #pragma unroll
    for (int ks = 0; ks < 2; ++ks) {
      int nlo = ks * 2, nhi = ks * 2 + 1;
      u32 a00 = __shfl((int)pk[nlo][0], laA), a01 = __shfl((int)pk[nlo][1], laA);
      u32 a10 = __shfl((int)pk[nhi][0], laA), a11 = __shfl((int)pk[nhi][1], laA);
      u32 b00 = __shfl((int)pk[nlo][0], laB), b01 = __shfl((int)pk[nlo][1], laB);
      u32 b10 = __shfl((int)pk[nhi][0], laB), b11 = __shfl((int)pk[nhi][1], laB);
      u32x4 wv;
      wv[0] = nbhi ? a10 : a00;
      wv[1] = nbhi ? a11 : a01;
      wv[2] = nbhi ? b10 : b00;
      wv[3] = nbhi ? b11 : b01;
      bf16x8 pa = __builtin_bit_cast(bf16x8, wv);
      #pragma unroll
      for (int nd = 0; nd < 4; ++nd) {
        int d = nd * 16 + l15;
        int psv = (ks * 4 + l4) ^ (d & 7);
        bf16x8 vf = *reinterpret_cast<const bf16x8*>(&Vs[buf][d * 64 + psv * 8]);
        o_[nd] = MFMA16(pa, vf, o_[nd]);
      }
    }
    __builtin_amdgcn_s_setprio(0);

    if (t < 15) __syncthreads();
    buf ^= 1;
  }

  float li0 = __shfl(l_, l4 * 4 + 0);
  float li1 = __shfl(l_, l4 * 4 + 1);
  float li2 = __shfl(l_, l4 * 4 + 2);
  float li3 = __shfl(l_, l4 * 4 + 3);
  float inv[4] = { 1.f / li0, 1.f / li1, 1.f / li2, 1.f / li3 };
  u16* ob = out + (size_t)b * NN * DH + h * HD;
  #pragma unroll
  for (int nd = 0; nd < 4; ++nd) {
    #pragma unroll
    for (int r = 0; r < 4; ++r) {
      int q = qt * 64 + wid * 16 + l4 * 4 + r;
      ob[(size_t)q * DH + nd * 16 + l15] = f2bf(o_[nd][r] * inv[r]);
    }
  }
}

extern "C" void kernel_launch(void* const* d_in, const int* in_sizes, int n_in,
                              void* d_out, int out_size, void* d_ws, size_t ws_size,
                              hipStream_t stream) {
  (void)in_sizes; (void)n_in; (void)out_size; (void)ws_size;
  const float* x      = (const float*)d_in[0];
  const float* te     = (const float*)d_in[1];
  const float* ln1_g  = (const float*)d_in[2];
  const float* ln1_b  = (const float*)d_in[3];
  const float* s1_w   = (const float*)d_in[4];
  const float* s1_b   = (const float*)d_in[5];
  const float* o1_w   = (const float*)d_in[6];
  const float* o1_b   = (const float*)d_in[7];
  const float* qkv_w  = (const float*)d_in[8];
  const float* qkv_b  = (const float*)d_in[9];
  const float* proj_w = (const float*)d_in[10];
  const float* proj_b = (const float*)d_in[11];
  const float* ln2_g  = (const float*)d_in[12];
  const float* ln2_b  = (const float*)d_in[13];
  const float* s2_w   = (const float*)d_in[14];
  const float* s2_b   = (const float*)d_in[15];
  const float* o2_w   = (const float*)d_in[16];
  const float* o2_b   = (const float*)d_in[17];
  const float* up_w   = (const float*)d_in[18];
  const float* up_b   = (const float*)d_in[19];
  const float* down_w = (const float*)d_in[20];
  const float* down_b = (const float*)d_in[21];

  char* ws = (char*)d_ws;
  size_t off = 0;
  auto alloc = [&](size_t bytes) { void* p = ws + off; off += (bytes + 255) & ~255ull; return p; };
  u16*   wq   = (u16*)  alloc((size_t)3072 * 1024 * 2);
  u16*   wp   = (u16*)  alloc((size_t)1024 * 1024 * 2);
  u16*   wu   = (u16*)  alloc((size_t)4096 * 1024 * 2);
  u16*   h1   = (u16*)  alloc((size_t)4096 * 1024 * 2);
  u16*   qkvb = (u16*)  alloc((size_t)4096 * 3072 * 2);
  u16*   att  = (u16*)  alloc((size_t)4096 * 1024 * 2);
  u16*   h2   = (u16*)  alloc((size_t)4096 * 1024 * 2);
  u16*   wd   = (u16*)  alloc((size_t)1024 * 4096 * 2);
  float* x2   = (float*)alloc((size_t)4096 * 1024 * 4);
  u16*   upb  = (u16*)  alloc((size_t)4096 * 4096 * 2);
  float* ada  = (float*)alloc((size_t)4 * 4 * 1024 * 4);
  float* sp1 = ada, *off1 = ada + 4096, *sp2 = ada + 8192, *off2 = ada + 12288;
  u16*   part = wq;
  u16*   vT   = h1;

  cvt_all_kernel<<<12288, 256, 0, stream>>>(qkv_w, proj_w, up_w, down_w, wq, wp, wu, wd);
  adaln_kernel<<<dim3(256, 4), 256, 0, stream>>>(te, s1_w, s1_b, o1_w, o1_b, s2_w, s2_b, o2_w, o2_b, ada);
  ln_mod_kernel<<<4096, 256, 0, stream>>>(x, ln1_g, ln1_b, sp1, off1, h1);
  gemmT_kernel<EPI_BF16><<<dim3(24, 16, 1), 512, 73728, stream>>>(h1, wq, qkv_b, nullptr, qkvb, 3072, 1024);
  vt_kernel<<<dim3(16, 64), 256, 0, stream>>>(qkvb, vT);
  attn_kernel<<<dim3(16, 64), 256, 0, stream>>>(qkvb, vT, att);
  gemmT_kernel<EPI_RES><<<dim3(8, 16, 1), 512, 73728, stream>>>(att, wp, proj_b, x, x2, 1024, 1024);
  ln_mod_kernel<<<4096, 256, 0, stream>>>(x2, ln2_g, ln2_b, sp2, off2, h2);
  gemmT_kernel<EPI_GELU><<<dim3(32, 16, 1), 512, 73728, stream>>>(h2, wu, up_b, nullptr, upb, 4096, 1024);
  gemmT_kernel<EPI_PART><<<dim3(8, 16, 4), 512, 73728, stream>>>(upb, wd, nullptr, nullptr, part, 1024, 4096);
  reduce4_kernel<<<4096, 256, 0, stream>>>(part, x2, down_b, te, (float*)d_out);
}

// Round 18
// 240.205 us; speedup vs baseline: 1.0122x; 1.0057x over previous
//
#include <hip/hip_runtime.h>
#include <hip/hip_bf16.h>
#include <math.h>

#define DH 1024
#define BB 4
#define NN 1024
#define NH 16
#define HD 64

typedef __attribute__((ext_vector_type(8))) short bf16x8;
typedef __attribute__((ext_vector_type(4))) float f32x4;
typedef __attribute__((ext_vector_type(4))) unsigned int u32x4;
typedef unsigned short u16;
typedef unsigned int u32;

static __device__ __forceinline__ u16 f2bf(float f) {
  __hip_bfloat16 h = __float2bfloat16(f);
  return *reinterpret_cast<u16*>(&h);
}
static __device__ __forceinline__ float bf2f(u16 x) {
  return __uint_as_float((unsigned)x << 16);
}

#define MFMA16(a, b, c) __builtin_amdgcn_mfma_f32_16x16x32_bf16(a, b, c, 0, 0, 0)
#define VMCNT(n) asm volatile("s_waitcnt vmcnt(" #n ")" ::: "memory")
#define MEMFENCE asm volatile("" ::: "memory")
#define BAR() do { __builtin_amdgcn_s_barrier(); MEMFENCE; } while (0)

static __device__ __forceinline__ void async16(const void* g, void* l) {
  __builtin_amdgcn_global_load_lds(
      (const __attribute__((address_space(1))) void*)g,
      (__attribute__((address_space(3))) void*)l, 16, 0, 0);
}

// ---------------- fused weight fp32 -> bf16 (all 4 weights, 1 launch) ----------------
__global__ void cvt_all_kernel(const float* __restrict__ wq, const float* __restrict__ wp,
                               const float* __restrict__ wu, const float* __restrict__ wd,
                               u16* __restrict__ oq, u16* __restrict__ op,
                               u16* __restrict__ ou, u16* __restrict__ od) {
  int i = blockIdx.x * 256 + threadIdx.x;  // float4 index, total 3145728
  const float* src; u16* dst; int off;
  if (i < 786432)            { src = wq; dst = oq; off = i; }
  else if (i < 1048576)      { src = wp; dst = op; off = i - 786432; }
  else if (i < 2097152)      { src = wu; dst = ou; off = i - 1048576; }
  else                       { src = wd; dst = od; off = i - 2097152; }
  float4 v = reinterpret_cast<const float4*>(src)[off];
  ushort4 o;
  o.x = f2bf(v.x); o.y = f2bf(v.y); o.z = f2bf(v.z); o.w = f2bf(v.w);
  reinterpret_cast<ushort4*>(dst)[off] = o;
}

// ---------------- adaLN small linears (4 rows of time_emb) ----------------
__global__ __launch_bounds__(256) void adaln_kernel(
    const float* __restrict__ e,
    const float* __restrict__ w_s1, const float* __restrict__ b_s1,
    const float* __restrict__ w_o1, const float* __restrict__ b_o1,
    const float* __restrict__ w_s2, const float* __restrict__ b_s2,
    const float* __restrict__ w_o2, const float* __restrict__ b_o2,
    float* __restrict__ out) {
  int tid = threadIdx.x, wid = tid >> 6, lane = tid & 63;
  int mat = blockIdx.y;
  const float* w; const float* bs; float addc;
  if (mat == 0)      { w = w_s1; bs = b_s1; addc = 1.f; }
  else if (mat == 1) { w = w_o1; bs = b_o1; addc = 0.f; }
  else if (mat == 2) { w = w_s2; bs = b_s2; addc = 1.f; }
  else               { w = w_o2; bs = b_o2; addc = 0.f; }
  int col = blockIdx.x * 4 + wid;
  float a0 = 0.f, a1 = 0.f, a2 = 0.f, a3 = 0.f;
  const float* wc_ = w + (size_t)col * DH;
  for (int i = 0; i < 16; ++i) {
    int k = i * 64 + lane;
    float wv = wc_[k];
    a0 += wv * e[k];
    a1 += wv * e[DH + k];
    a2 += wv * e[2 * DH + k];
    a3 += wv * e[3 * DH + k];
  }
  #pragma unroll
  for (int msk = 32; msk; msk >>= 1) {
    a0 += __shfl_xor(a0, msk); a1 += __shfl_xor(a1, msk);
    a2 += __shfl_xor(a2, msk); a3 += __shfl_xor(a3, msk);
  }
  if (lane == 0) {
    float bb = bs[col] + addc;
    out[mat * (4 * DH) + 0 * DH + col] = a0 + bb;
    out[mat * (4 * DH) + 1 * DH + col] = a1 + bb;
    out[mat * (4 * DH) + 2 * DH + col] = a2 + bb;
    out[mat * (4 * DH) + 3 * DH + col] = a3 + bb;
  }
}

// ---------------- fused LayerNorm + adaLN modulate -> bf16 ----------------
__global__ __launch_bounds__(256) void ln_mod_kernel(
    const float* __restrict__ x, const float* __restrict__ g, const float* __restrict__ bta,
    const float* __restrict__ sp, const float* __restrict__ off, u16* __restrict__ out) {
  int row = blockIdx.x;
  int b = row >> 10;
  int tid = threadIdx.x;
  int wid = tid >> 6, lane = tid & 63;
  const float4 xv = reinterpret_cast<const float4*>(x + (size_t)row * DH)[tid];
  float s = xv.x + xv.y + xv.z + xv.w;
  float ss = xv.x * xv.x + xv.y * xv.y + xv.z * xv.z + xv.w * xv.w;
  #pragma unroll
  for (int m = 32; m; m >>= 1) { s += __shfl_xor(s, m); ss += __shfl_xor(ss, m); }
  __shared__ float red[8];
  if (lane == 0) { red[wid] = s; red[4 + wid] = ss; }
  __syncthreads();
  s = red[0] + red[1] + red[2] + red[3];
  ss = red[4] + red[5] + red[6] + red[7];
  float mean = s * (1.f / DH);
  float var = ss * (1.f / DH) - mean * mean;
  float rstd = rsqrtf(var + 1e-5f);
  int c = tid * 4;
  const float* spb = sp + b * DH + c;
  const float* offb = off + b * DH + c;
  float y0 = (xv.x - mean) * rstd * g[c + 0] + bta[c + 0];
  float y1 = (xv.y - mean) * rstd * g[c + 1] + bta[c + 1];
  float y2 = (xv.z - mean) * rstd * g[c + 2] + bta[c + 2];
  float y3 = (xv.w - mean) * rstd * g[c + 3] + bta[c + 3];
  ushort4 o;
  o.x = f2bf(spb[0] * y0 + offb[0]);
  o.y = f2bf(spb[1] * y1 + offb[1]);
  o.z = f2bf(spb[2] * y2 + offb[2]);
  o.w = f2bf(spb[3] * y3 + offb[3]);
  reinterpret_cast<ushort4*>(out + (size_t)row * DH)[tid] = o;
}

// ======== 256x128 tile, BK=32, 3-deep rotating pipeline, ONE barrier per K-step ========
// Round-13/15 measured-best config (128x32 wave tiles). KT hard-coded 32.
// EPI_BF16V: qkv variant that also writes the transposed V copy (cols >= 2048) to vT.
enum { EPI_BF16 = 0, EPI_GELU = 1, EPI_PART = 2, EPI_RES = 3, EPI_BF16V = 4 };

template <int EPI>
__global__ __launch_bounds__(512, 2) void gemmT_kernel(
    const u16* __restrict__ A, const u16* __restrict__ W,
    const float* __restrict__ bias, const float* __restrict__ resid,
    void* __restrict__ outp, u16* __restrict__ vTout, int N, int K) {
  extern __shared__ u16 lds[];
  u16* Ab = lds;            // [3][256*32] u16 (48 KiB)
  u16* Bb = lds + 24576;    // [3][128*32] u16 (24 KiB)
  int tid = threadIdx.x;
  int wid = tid >> 6, lane = tid & 63;
  int l15 = lane & 15, l4 = lane >> 4;
  int wr = wid >> 2, wc = wid & 3;   // 2M x 4N waves, per-wave 128x32 out

  int nwg = gridDim.x * gridDim.y;
  int lin = blockIdx.y * gridDim.x + blockIdx.x;
  int q8 = nwg >> 3;
  int lin2 = (lin & 7) * q8 + (lin >> 3);
  int bx = lin2 % gridDim.x, by = lin2 / gridDim.x;
  int m0 = by * 256, n0 = bx * 128;
  int k0 = blockIdx.z * 1024;   // KT=32 -> 1024 K per z-slice

  f32x4 acc[8][2] = {};

  const u16* Abase = A + (size_t)m0 * K + k0;
  const u16* Wbase = W + (size_t)n0 * K + k0;
  int i0 = tid, i1 = 512 + tid;
  int r0 = i0 >> 2, c0 = (i0 & 3) ^ ((r0 >> 1) & 3);
  int r1 = i1 >> 2, c1 = (i1 & 3) ^ ((r1 >> 1) & 3);
  int rB = tid >> 2, cB = (tid & 3) ^ ((rB >> 1) & 3);
  size_t gA0 = (size_t)r0 * K + c0 * 8;
  size_t gA1 = (size_t)r1 * K + c1 * 8;
  size_t gB0 = (size_t)rB * K + cB * 8;
  int lbA0 = (wid * 64) * 8;
  int lbA1 = (512 + wid * 64) * 8;

  auto stage = [&](int tt, int bi) {
    int qa = bi * 8192, qb = bi * 4096;
    const u16* Ak = Abase + tt * 32;
    const u16* Wk = Wbase + tt * 32;
    async16(Ak + gA0, &Ab[qa + lbA0]);
    async16(Ak + gA1, &Ab[qa + lbA1]);
    async16(Wk + gB0, &Bb[qb + lbA0]);
  };

  auto compute = [&](int bi) {
    int qa = bi * 8192, qb = bi * 4096;
    bf16x8 af[8], bfr[2];
    #pragma unroll
    for (int m = 0; m < 8; ++m) {
      int row = wr * 128 + m * 16 + l15;
      int ps = l4 ^ ((row >> 1) & 3);
      af[m] = *reinterpret_cast<const bf16x8*>(&Ab[qa + row * 32 + ps * 8]);
    }
    #pragma unroll
    for (int n = 0; n < 2; ++n) {
      int row = wc * 32 + n * 16 + l15;
      int ps = l4 ^ ((row >> 1) & 3);
      bfr[n] = *reinterpret_cast<const bf16x8*>(&Bb[qb + row * 32 + ps * 8]);
    }
    #pragma unroll
    for (int m = 0; m < 8; ++m)
      #pragma unroll
      for (int n = 0; n < 2; ++n)
        acc[m][n] = MFMA16(af[m], bfr[n], acc[m][n]);
  };

  stage(0, 0);
  stage(1, 1);
  for (int tb = 0; tb < 30; tb += 3) {
    VMCNT(3); BAR(); stage(tb + 2, 2); compute(0);
    VMCNT(3); BAR(); stage(tb + 3, 0); compute(1);
    VMCNT(3); BAR(); stage(tb + 4, 1); compute(2);
  }
  VMCNT(3); BAR(); compute(0);   // t=30
  VMCNT(0); BAR(); compute(1);   // t=31

  int M = gridDim.y * 256;
  u16* pout = (u16*)outp + (size_t)blockIdx.z * M * N;   // bf16 partials for split-K
  #pragma unroll
  for (int n = 0; n < 2; ++n) {
    int col = n0 + wc * 32 + n * 16 + l15;
    float bv = (EPI == EPI_PART) ? 0.f : bias[col];
    #pragma unroll
    for (int m = 0; m < 8; ++m) {
      ushort4 vq;
      #pragma unroll
      for (int r = 0; r < 4; ++r) {
        int rowg = m0 + wr * 128 + m * 16 + l4 * 4 + r;
        float v = acc[m][n][r] + bv;
        if (EPI == EPI_GELU) {
          v = 0.5f * v * (1.f + erff(v * 0.70710678118f));
          ((u16*)outp)[(size_t)rowg * N + col] = f2bf(v);
        } else if (EPI == EPI_BF16 || EPI == EPI_BF16V) {
          u16 bw = f2bf(v);
          ((u16*)outp)[(size_t)rowg * N + col] = bw;
          if (EPI == EPI_BF16V) {
            if (r == 0) vq.x = bw; else if (r == 1) vq.y = bw;
            else if (r == 2) vq.z = bw; else vq.w = bw;
          }
        } else if (EPI == EPI_RES) {
          ((float*)outp)[(size_t)rowg * N + col] = v + resid[(size_t)rowg * N + col];
        } else {
          pout[(size_t)rowg * N + col] = f2bf(v);
        }
      }
      if (EPI == EPI_BF16V && col >= 2048) {
        // transposed V copy: vT[(b*16+h)*64 + d][token], 4 consecutive tokens
        int vcol = col - 2048;
        int h = vcol >> 6, d = vcol & 63;
        int rowg0 = m0 + wr * 128 + m * 16 + l4 * 4;
        int b = rowg0 >> 10, tok = rowg0 & 1023;
        *reinterpret_cast<ushort4*>(
            vTout + (((size_t)(b * 16 + h) * 64 + d) << 10) + tok) = vq;
      }
    }
  }
}

// ---------------- split-K reduce (bf16 partials) + te passthrough ----------------
__global__ __launch_bounds__(256) void reduce4_kernel(
    const u16* __restrict__ part, const float* __restrict__ x2,
    const float* __restrict__ bias, const float* __restrict__ te,
    float* __restrict__ out) {
  size_t i = (size_t)blockIdx.x * 256 + threadIdx.x;
  const size_t MN = (size_t)4096 * 1024;
  float4 xr = reinterpret_cast<const float4*>(x2)[i];
  int col = (int)((i * 4) & 1023);
  float4 bv = *reinterpret_cast<const float4*>(&bias[col]);
  float a0 = xr.x + bv.x, a1 = xr.y + bv.y, a2 = xr.z + bv.z, a3 = xr.w + bv.w;
  #pragma unroll
  for (int p = 0; p < 4; ++p) {
    ushort4 u = reinterpret_cast<const ushort4*>(part + p * MN)[i];
    a0 += bf2f(u.x); a1 += bf2f(u.y); a2 += bf2f(u.z); a3 += bf2f(u.w);
  }
  float4 o; o.x = a0; o.y = a1; o.z = a2; o.w = a3;
  reinterpret_cast<float4*>(out)[i] = o;
  if (blockIdx.x < 16) {
    int ii = blockIdx.x * 256 + threadIdx.x;
    out[4096 * 1024 + ii] = te[ii];
  }
}

// ---------------- flash attention: swapped QK^T, fully in-register softmax/P ----------------
// Round-15 measured-best version.
__global__ __launch_bounds__(256, 4) void attn_kernel(
    const u16* __restrict__ qkv, const u16* __restrict__ vT, u16* __restrict__ out) {
  __shared__ __align__(16) u16 Ks[2][4096];
  __shared__ __align__(16) u16 Vs[2][4096];
  int tid = threadIdx.x, wid = tid >> 6, lane = tid & 63;
  int l15 = lane & 15, l4 = lane >> 4;
  int L = blockIdx.y * gridDim.x + blockIdx.x;
  int qt = (L >> 3) & 15;
  int bh = (L & 7) | ((L >> 7) << 3);
  int b = bh >> 4, h = bh & 15;
  const size_t SN = 3 * DH;
  const u16* qb = qkv + (size_t)b * NN * SN + h * HD;
  const u16* kb = qb + DH;
  const u16* vtb = vT + (size_t)bh * 64 * 1024;

  int qrow = qt * 64 + wid * 16 + l15;
  bf16x8 qf[2];
  #pragma unroll
  for (int ks = 0; ks < 2; ++ks)
    qf[ks] = *reinterpret_cast<const bf16x8*>(qb + (size_t)qrow * SN + ks * 32 + l4 * 8);

  float m_ = -1e30f, l_ = 0.f;
  f32x4 o_[4] = {};

  int laA = ((l4 * 2) & 3) * 16 + l15;
  int laB = ((l4 * 2 + 1) & 3) * 16 + l15;
  bool nbhi = (l4 >> 1) != 0;

  int iA = tid, iB = 256 + tid;
  int jA = iA >> 3, sA = iA & 7, gsA = sA ^ (jA & 7);
  int jB = iB >> 3, sB = iB & 7, gsB = sB ^ (jB & 7);

  auto stageKV = [&](int bufn, int t) {
    const u16* kt = kb + (size_t)t * 64 * SN;
    async16(kt + (size_t)jA * SN + gsA * 8, &Ks[bufn][iA * 8]);
    async16(kt + (size_t)jB * SN + gsB * 8, &Ks[bufn][iB * 8]);
    const u16* vt = vtb + (size_t)t * 64;
    async16(vt + (size_t)jA * 1024 + gsA * 8, &Vs[bufn][iA * 8]);
    async16(vt + (size_t)jB * 1024 + gsB * 8, &Vs[bufn][iB * 8]);
  };

  stageKV(0, 0);
  __syncthreads();

  int buf = 0;
  for (int t = 0; t < 16; ++t) {
    if (t < 15) stageKV(buf ^ 1, t + 1);

    f32x4 sa[4];
    #pragma unroll
    for (int nb = 0; nb < 4; ++nb) {
      f32x4 s = {};
      #pragma unroll
      for (int ks = 0; ks < 2; ++ks) {
        int j = nb * 16 + l15;
        int ps = (ks * 4 + l4) ^ (j & 7);
        bf16x8 kf = *reinterpret_cast<const bf16x8*>(&Ks[buf][j * 64 + ps * 8]);
        s = MFMA16(kf, qf[ks], s);
      }
      sa[nb] = s * 0.125f;
    }

    float pm = sa[0][0];
    #pragma unroll
    for (int nb = 0; nb < 4; ++nb)
      #pragma unroll
      for (int r = 0; r < 4; ++r)
        if (nb || r) pm = fmaxf(pm, sa[nb][r]);
    pm = fmaxf(pm, __shfl_xor(pm, 16));
    pm = fmaxf(pm, __shfl_xor(pm, 32));

    if (!__all(pm - m_ <= 8.f)) {
      float mn = fmaxf(m_, pm);
      float corr = __expf(m_ - mn);
      m_ = mn;
      l_ *= corr;
      float c0 = __shfl(corr, l4 * 4 + 0);
      float c1 = __shfl(corr, l4 * 4 + 1);
      float c2 = __shfl(corr, l4 * 4 + 2);
      float c3 = __shfl(corr, l4 * 4 + 3);
      #pragma unroll
      for (int nd = 0; nd < 4; ++nd) {
        o_[nd][0] *= c0; o_[nd][1] *= c1; o_[nd][2] *= c2; o_[nd][3] *= c3;
      }
    }

    float ts = 0.f;
    u32 pk[4][2];
    #pragma unroll
    for (int nb = 0; nb < 4; ++nb) {
      float p0 = __expf(sa[nb][0] - m_);
      float p1 = __expf(sa[nb][1] - m_);
      float p2 = __expf(sa[nb][2] - m_);
      float p3 = __expf(sa[nb][3] - m_);
      ts += (p0 + p1) + (p2 + p3);
      pk[nb][0] = (u32)f2bf(p0) | ((u32)f2bf(p1) << 16);
      pk[nb][1] = (u32)f2bf(p2) | ((u32)f2bf(p3) << 16);
    }
    ts += __shfl_xor(ts, 16);
    ts += __shfl_xor(ts, 32);
    l_ += ts;

    __builtin_amdgcn_s_setprio(1);
    #pragma unroll
    for (int ks = 0; ks < 2; ++ks) {
      int nlo = ks * 2, nhi = ks * 2 + 1;
      u32 a00 = __shfl((int)pk[nlo][0], laA), a01 = __shfl((int)pk[nlo][1], laA);
      u32 a10 = __shfl((int)pk[nhi][0], laA), a11 = __shfl((int)pk[nhi][1], laA);
      u32 b00 = __shfl((int)pk[nlo][0], laB), b01 = __shfl((int)pk[nlo][1], laB);
      u32 b10 = __shfl((int)pk[nhi][0], laB), b11 = __shfl((int)pk[nhi][1], laB);
      u32x4 wv;
      wv[0] = nbhi ? a10 : a00;
      wv[1] = nbhi ? a11 : a01;
      wv[2] = nbhi ? b10 : b00;
      wv[3] = nbhi ? b11 : b01;
      bf16x8 pa = __builtin_bit_cast(bf16x8, wv);
      #pragma unroll
      for (int nd = 0; nd < 4; ++nd) {
        int d = nd * 16 + l15;
        int psv = (ks * 4 + l4) ^ (d & 7);
        bf16x8 vf = *reinterpret_cast<const bf16x8*>(&Vs[buf][d * 64 + psv * 8]);
        o_[nd] = MFMA16(pa, vf, o_[nd]);
      }
    }
    __builtin_amdgcn_s_setprio(0);

    if (t < 15) __syncthreads();
    buf ^= 1;
  }

  float li0 = __shfl(l_, l4 * 4 + 0);
  float li1 = __shfl(l_, l4 * 4 + 1);
  float li2 = __shfl(l_, l4 * 4 + 2);
  float li3 = __shfl(l_, l4 * 4 + 3);
  float inv[4] = { 1.f / li0, 1.f / li1, 1.f / li2, 1.f / li3 };
  u16* ob = out + (size_t)b * NN * DH + h * HD;
  #pragma unroll
  for (int nd = 0; nd < 4; ++nd) {
    #pragma unroll
    for (int r = 0; r < 4; ++r) {
      int q = qt * 64 + wid * 16 + l4 * 4 + r;
      ob[(size_t)q * DH + nd * 16 + l15] = f2bf(o_[nd][r] * inv[r]);
    }
  }
}

extern "C" void kernel_launch(void* const* d_in, const int* in_sizes, int n_in,
                              void* d_out, int out_size, void* d_ws, size_t ws_size,
                              hipStream_t stream) {
  (void)in_sizes; (void)n_in; (void)out_size; (void)ws_size;
  const float* x      = (const float*)d_in[0];
  const float* te     = (const float*)d_in[1];
  const float* ln1_g  = (const float*)d_in[2];
  const float* ln1_b  = (const float*)d_in[3];
  const float* s1_w   = (const float*)d_in[4];
  const float* s1_b   = (const float*)d_in[5];
  const float* o1_w   = (const float*)d_in[6];
  const float* o1_b   = (const float*)d_in[7];
  const float* qkv_w  = (const float*)d_in[8];
  const float* qkv_b  = (const float*)d_in[9];
  const float* proj_w = (const float*)d_in[10];
  const float* proj_b = (const float*)d_in[11];
  const float* ln2_g  = (const float*)d_in[12];
  const float* ln2_b  = (const float*)d_in[13];
  const float* s2_w   = (const float*)d_in[14];
  const float* s2_b   = (const float*)d_in[15];
  const float* o2_w   = (const float*)d_in[16];
  const float* o2_b   = (const float*)d_in[17];
  const float* up_w   = (const float*)d_in[18];
  const float* up_b   = (const float*)d_in[19];
  const float* down_w = (const float*)d_in[20];
  const float* down_b = (const float*)d_in[21];

  char* ws = (char*)d_ws;
  size_t off = 0;
  auto alloc = [&](size_t bytes) { void* p = ws + off; off += (bytes + 255) & ~255ull; return p; };
  u16*   wq   = (u16*)  alloc((size_t)3072 * 1024 * 2);
  u16*   wp   = (u16*)  alloc((size_t)1024 * 1024 * 2);
  u16*   wu   = (u16*)  alloc((size_t)4096 * 1024 * 2);
  u16*   h1   = (u16*)  alloc((size_t)4096 * 1024 * 2);
  u16*   qkvb = (u16*)  alloc((size_t)4096 * 3072 * 2);
  u16*   att  = (u16*)  alloc((size_t)4096 * 1024 * 2);
  u16*   h2   = (u16*)  alloc((size_t)4096 * 1024 * 2);
  u16*   wd   = (u16*)  alloc((size_t)1024 * 4096 * 2);
  float* x2   = (float*)alloc((size_t)4096 * 1024 * 4);
  u16*   upb  = (u16*)  alloc((size_t)4096 * 4096 * 2);
  u16*   vT   = (u16*)  alloc((size_t)64 * 64 * 1024 * 2);   // 8 MiB, written by qkv epilogue
  float* ada  = (float*)alloc((size_t)4 * 4 * 1024 * 4);
  float* sp1 = ada, *off1 = ada + 4096, *sp2 = ada + 8192, *off2 = ada + 12288;
  u16*   part = wq;   // overlays dead region (wq dead after qkv GEMM)

  cvt_all_kernel<<<12288, 256, 0, stream>>>(qkv_w, proj_w, up_w, down_w, wq, wp, wu, wd);
  adaln_kernel<<<dim3(256, 4), 256, 0, stream>>>(te, s1_w, s1_b, o1_w, o1_b, s2_w, s2_b, o2_w, o2_b, ada);
  ln_mod_kernel<<<4096, 256, 0, stream>>>(x, ln1_g, ln1_b, sp1, off1, h1);
  gemmT_kernel<EPI_BF16V><<<dim3(24, 16, 1), 512, 73728, stream>>>(h1, wq, qkv_b, nullptr, qkvb, vT, 3072, 1024);
  attn_kernel<<<dim3(16, 64), 256, 0, stream>>>(qkvb, vT, att);
  gemmT_kernel<EPI_RES><<<dim3(8, 16, 1), 512, 73728, stream>>>(att, wp, proj_b, x, x2, nullptr, 1024, 1024);
  ln_mod_kernel<<<4096, 256, 0, stream>>>(x2, ln2_g, ln2_b, sp2, off2, h2);
  gemmT_kernel<EPI_GELU><<<dim3(32, 16, 1), 512, 73728, stream>>>(h2, wu, up_b, nullptr, upb, nullptr, 4096, 1024);
  gemmT_kernel<EPI_PART><<<dim3(8, 16, 4), 512, 73728, stream>>>(upb, wd, nullptr, nullptr, part, nullptr, 1024, 4096);
  reduce4_kernel<<<4096, 256, 0, stream>>>(part, x2, down_b, te, (float*)d_out);
}

// Round 19
// 237.867 us; speedup vs baseline: 1.0222x; 1.0098x over previous
//
#include <hip/hip_runtime.h>
#include <hip/hip_bf16.h>
#include <math.h>

#define DH 1024
#define BB 4
#define NN 1024
#define NH 16
#define HD 64

typedef __attribute__((ext_vector_type(8))) short bf16x8;
typedef __attribute__((ext_vector_type(4))) float f32x4;
typedef __attribute__((ext_vector_type(4))) unsigned int u32x4;
typedef unsigned short u16;
typedef unsigned int u32;

static __device__ __forceinline__ u16 f2bf(float f) {
  __hip_bfloat16 h = __float2bfloat16(f);
  return *reinterpret_cast<u16*>(&h);
}
static __device__ __forceinline__ float bf2f(u16 x) {
  return __uint_as_float((unsigned)x << 16);
}

#define MFMA16(a, b, c) __builtin_amdgcn_mfma_f32_16x16x32_bf16(a, b, c, 0, 0, 0)
#define VMCNT(n) asm volatile("s_waitcnt vmcnt(" #n ")" ::: "memory")
#define MEMFENCE asm volatile("" ::: "memory")
#define BAR() do { __builtin_amdgcn_s_barrier(); MEMFENCE; } while (0)

static __device__ __forceinline__ void async16(const void* g, void* l) {
  __builtin_amdgcn_global_load_lds(
      (const __attribute__((address_space(1))) void*)g,
      (__attribute__((address_space(3))) void*)l, 16, 0, 0);
}

// ---------------- fused weight fp32 -> bf16 (all 4 weights, 1 launch) ----------------
__global__ void cvt_all_kernel(const float* __restrict__ wq, const float* __restrict__ wp,
                               const float* __restrict__ wu, const float* __restrict__ wd,
                               u16* __restrict__ oq, u16* __restrict__ op,
                               u16* __restrict__ ou, u16* __restrict__ od) {
  int i = blockIdx.x * 256 + threadIdx.x;  // float4 index, total 3145728
  const float* src; u16* dst; int off;
  if (i < 786432)            { src = wq; dst = oq; off = i; }
  else if (i < 1048576)      { src = wp; dst = op; off = i - 786432; }
  else if (i < 2097152)      { src = wu; dst = ou; off = i - 1048576; }
  else                       { src = wd; dst = od; off = i - 2097152; }
  float4 v = reinterpret_cast<const float4*>(src)[off];
  ushort4 o;
  o.x = f2bf(v.x); o.y = f2bf(v.y); o.z = f2bf(v.z); o.w = f2bf(v.w);
  reinterpret_cast<ushort4*>(dst)[off] = o;
}

// ---------------- adaLN small linears (4 rows of time_emb) ----------------
__global__ __launch_bounds__(256) void adaln_kernel(
    const float* __restrict__ e,
    const float* __restrict__ w_s1, const float* __restrict__ b_s1,
    const float* __restrict__ w_o1, const float* __restrict__ b_o1,
    const float* __restrict__ w_s2, const float* __restrict__ b_s2,
    const float* __restrict__ w_o2, const float* __restrict__ b_o2,
    float* __restrict__ out) {
  int tid = threadIdx.x, wid = tid >> 6, lane = tid & 63;
  int mat = blockIdx.y;
  const float* w; const float* bs; float addc;
  if (mat == 0)      { w = w_s1; bs = b_s1; addc = 1.f; }
  else if (mat == 1) { w = w_o1; bs = b_o1; addc = 0.f; }
  else if (mat == 2) { w = w_s2; bs = b_s2; addc = 1.f; }
  else               { w = w_o2; bs = b_o2; addc = 0.f; }
  int col = blockIdx.x * 4 + wid;
  float a0 = 0.f, a1 = 0.f, a2 = 0.f, a3 = 0.f;
  const float* wc_ = w + (size_t)col * DH;
  for (int i = 0; i < 16; ++i) {
    int k = i * 64 + lane;
    float wv = wc_[k];
    a0 += wv * e[k];
    a1 += wv * e[DH + k];
    a2 += wv * e[2 * DH + k];
    a3 += wv * e[3 * DH + k];
  }
  #pragma unroll
  for (int msk = 32; msk; msk >>= 1) {
    a0 += __shfl_xor(a0, msk); a1 += __shfl_xor(a1, msk);
    a2 += __shfl_xor(a2, msk); a3 += __shfl_xor(a3, msk);
  }
  if (lane == 0) {
    float bb = bs[col] + addc;
    out[mat * (4 * DH) + 0 * DH + col] = a0 + bb;
    out[mat * (4 * DH) + 1 * DH + col] = a1 + bb;
    out[mat * (4 * DH) + 2 * DH + col] = a2 + bb;
    out[mat * (4 * DH) + 3 * DH + col] = a3 + bb;
  }
}

// ---------------- fused LayerNorm + adaLN modulate -> bf16 (fp32 input) ----------------
__global__ __launch_bounds__(256) void ln_mod_kernel(
    const float* __restrict__ x, const float* __restrict__ g, const float* __restrict__ bta,
    const float* __restrict__ sp, const float* __restrict__ off, u16* __restrict__ out) {
  int row = blockIdx.x;
  int b = row >> 10;
  int tid = threadIdx.x;
  int wid = tid >> 6, lane = tid & 63;
  const float4 xv = reinterpret_cast<const float4*>(x + (size_t)row * DH)[tid];
  float s = xv.x + xv.y + xv.z + xv.w;
  float ss = xv.x * xv.x + xv.y * xv.y + xv.z * xv.z + xv.w * xv.w;
  #pragma unroll
  for (int m = 32; m; m >>= 1) { s += __shfl_xor(s, m); ss += __shfl_xor(ss, m); }
  __shared__ float red[8];
  if (lane == 0) { red[wid] = s; red[4 + wid] = ss; }
  __syncthreads();
  s = red[0] + red[1] + red[2] + red[3];
  ss = red[4] + red[5] + red[6] + red[7];
  float mean = s * (1.f / DH);
  float var = ss * (1.f / DH) - mean * mean;
  float rstd = rsqrtf(var + 1e-5f);
  int c = tid * 4;
  const float* spb = sp + b * DH + c;
  const float* offb = off + b * DH + c;
  float y0 = (xv.x - mean) * rstd * g[c + 0] + bta[c + 0];
  float y1 = (xv.y - mean) * rstd * g[c + 1] + bta[c + 1];
  float y2 = (xv.z - mean) * rstd * g[c + 2] + bta[c + 2];
  float y3 = (xv.w - mean) * rstd * g[c + 3] + bta[c + 3];
  ushort4 o;
  o.x = f2bf(spb[0] * y0 + offb[0]);
  o.y = f2bf(spb[1] * y1 + offb[1]);
  o.z = f2bf(spb[2] * y2 + offb[2]);
  o.w = f2bf(spb[3] * y3 + offb[3]);
  reinterpret_cast<ushort4*>(out + (size_t)row * DH)[tid] = o;
}

// ---------------- fused LayerNorm + adaLN modulate -> bf16 (bf16 input) ----------------
__global__ __launch_bounds__(256) void ln_mod_bf16_kernel(
    const u16* __restrict__ x, const float* __restrict__ g, const float* __restrict__ bta,
    const float* __restrict__ sp, const float* __restrict__ off, u16* __restrict__ out) {
  int row = blockIdx.x;
  int b = row >> 10;
  int tid = threadIdx.x;
  int wid = tid >> 6, lane = tid & 63;
  ushort4 xu = reinterpret_cast<const ushort4*>(x + (size_t)row * DH)[tid];
  float x0 = bf2f(xu.x), x1 = bf2f(xu.y), x2v = bf2f(xu.z), x3 = bf2f(xu.w);
  float s = x0 + x1 + x2v + x3;
  float ss = x0 * x0 + x1 * x1 + x2v * x2v + x3 * x3;
  #pragma unroll
  for (int m = 32; m; m >>= 1) { s += __shfl_xor(s, m); ss += __shfl_xor(ss, m); }
  __shared__ float red[8];
  if (lane == 0) { red[wid] = s; red[4 + wid] = ss; }
  __syncthreads();
  s = red[0] + red[1] + red[2] + red[3];
  ss = red[4] + red[5] + red[6] + red[7];
  float mean = s * (1.f / DH);
  float var = ss * (1.f / DH) - mean * mean;
  float rstd = rsqrtf(var + 1e-5f);
  int c = tid * 4;
  const float* spb = sp + b * DH + c;
  const float* offb = off + b * DH + c;
  float y0 = (x0 - mean) * rstd * g[c + 0] + bta[c + 0];
  float y1 = (x1 - mean) * rstd * g[c + 1] + bta[c + 1];
  float y2 = (x2v - mean) * rstd * g[c + 2] + bta[c + 2];
  float y3 = (x3 - mean) * rstd * g[c + 3] + bta[c + 3];
  ushort4 o;
  o.x = f2bf(spb[0] * y0 + offb[0]);
  o.y = f2bf(spb[1] * y1 + offb[1]);
  o.z = f2bf(spb[2] * y2 + offb[2]);
  o.w = f2bf(spb[3] * y3 + offb[3]);
  reinterpret_cast<ushort4*>(out + (size_t)row * DH)[tid] = o;
}

// ======== 256x128 tile, BK=32, 3-deep rotating pipeline, ONE barrier per K-step ========
// EPI_BF16V: qkv variant that also writes the transposed V copy (cols >= 2048) to vT.
// EPI_RES: writes bf16 (v + resid) -- x2 stream kept in bf16.
enum { EPI_BF16 = 0, EPI_GELU = 1, EPI_PART = 2, EPI_RES = 3, EPI_BF16V = 4 };

template <int EPI>
__global__ __launch_bounds__(512, 2) void gemmT_kernel(
    const u16* __restrict__ A, const u16* __restrict__ W,
    const float* __restrict__ bias, const float* __restrict__ resid,
    void* __restrict__ outp, u16* __restrict__ vTout, int N, int K) {
  extern __shared__ u16 lds[];
  u16* Ab = lds;            // [3][256*32] u16 (48 KiB)
  u16* Bb = lds + 24576;    // [3][128*32] u16 (24 KiB)
  int tid = threadIdx.x;
  int wid = tid >> 6, lane = tid & 63;
  int l15 = lane & 15, l4 = lane >> 4;
  int wr = wid >> 2, wc = wid & 3;   // 2M x 4N waves, per-wave 128x32 out

  int nwg = gridDim.x * gridDim.y;
  int lin = blockIdx.y * gridDim.x + blockIdx.x;
  int q8 = nwg >> 3;
  int lin2 = (lin & 7) * q8 + (lin >> 3);
  int bx = lin2 % gridDim.x, by = lin2 / gridDim.x;
  int m0 = by * 256, n0 = bx * 128;
  int k0 = blockIdx.z * 1024;   // KT=32 -> 1024 K per z-slice

  f32x4 acc[8][2] = {};

  const u16* Abase = A + (size_t)m0 * K + k0;
  const u16* Wbase = W + (size_t)n0 * K + k0;
  int i0 = tid, i1 = 512 + tid;
  int r0 = i0 >> 2, c0 = (i0 & 3) ^ ((r0 >> 1) & 3);
  int r1 = i1 >> 2, c1 = (i1 & 3) ^ ((r1 >> 1) & 3);
  int rB = tid >> 2, cB = (tid & 3) ^ ((rB >> 1) & 3);
  size_t gA0 = (size_t)r0 * K + c0 * 8;
  size_t gA1 = (size_t)r1 * K + c1 * 8;
  size_t gB0 = (size_t)rB * K + cB * 8;
  int lbA0 = (wid * 64) * 8;
  int lbA1 = (512 + wid * 64) * 8;

  auto stage = [&](int tt, int bi) {
    int qa = bi * 8192, qb = bi * 4096;
    const u16* Ak = Abase + tt * 32;
    const u16* Wk = Wbase + tt * 32;
    async16(Ak + gA0, &Ab[qa + lbA0]);
    async16(Ak + gA1, &Ab[qa + lbA1]);
    async16(Wk + gB0, &Bb[qb + lbA0]);
  };

  auto compute = [&](int bi) {
    int qa = bi * 8192, qb = bi * 4096;
    bf16x8 af[8], bfr[2];
    #pragma unroll
    for (int m = 0; m < 8; ++m) {
      int row = wr * 128 + m * 16 + l15;
      int ps = l4 ^ ((row >> 1) & 3);
      af[m] = *reinterpret_cast<const bf16x8*>(&Ab[qa + row * 32 + ps * 8]);
    }
    #pragma unroll
    for (int n = 0; n < 2; ++n) {
      int row = wc * 32 + n * 16 + l15;
      int ps = l4 ^ ((row >> 1) & 3);
      bfr[n] = *reinterpret_cast<const bf16x8*>(&Bb[qb + row * 32 + ps * 8]);
    }
    #pragma unroll
    for (int m = 0; m < 8; ++m)
      #pragma unroll
      for (int n = 0; n < 2; ++n)
        acc[m][n] = MFMA16(af[m], bfr[n], acc[m][n]);
  };

  stage(0, 0);
  stage(1, 1);
  for (int tb = 0; tb < 30; tb += 3) {
    VMCNT(3); BAR(); stage(tb + 2, 2); compute(0);
    VMCNT(3); BAR(); stage(tb + 3, 0); compute(1);
    VMCNT(3); BAR(); stage(tb + 4, 1); compute(2);
  }
  VMCNT(3); BAR(); compute(0);   // t=30
  VMCNT(0); BAR(); compute(1);   // t=31

  int M = gridDim.y * 256;
  u16* pout = (u16*)outp + (size_t)blockIdx.z * M * N;   // bf16 partials for split-K
  #pragma unroll
  for (int n = 0; n < 2; ++n) {
    int col = n0 + wc * 32 + n * 16 + l15;
    float bv = (EPI == EPI_PART) ? 0.f : bias[col];
    #pragma unroll
    for (int m = 0; m < 8; ++m) {
      ushort4 vq;
      #pragma unroll
      for (int r = 0; r < 4; ++r) {
        int rowg = m0 + wr * 128 + m * 16 + l4 * 4 + r;
        float v = acc[m][n][r] + bv;
        if (EPI == EPI_GELU) {
          v = 0.5f * v * (1.f + erff(v * 0.70710678118f));
          ((u16*)outp)[(size_t)rowg * N + col] = f2bf(v);
        } else if (EPI == EPI_BF16 || EPI == EPI_BF16V) {
          u16 bw = f2bf(v);
          ((u16*)outp)[(size_t)rowg * N + col] = bw;
          if (EPI == EPI_BF16V) {
            if (r == 0) vq.x = bw; else if (r == 1) vq.y = bw;
            else if (r == 2) vq.z = bw; else vq.w = bw;
          }
        } else if (EPI == EPI_RES) {
          ((u16*)outp)[(size_t)rowg * N + col] =
              f2bf(v + resid[(size_t)rowg * N + col]);
        } else {
          pout[(size_t)rowg * N + col] = f2bf(v);
        }
      }
      if (EPI == EPI_BF16V && col >= 2048) {
        int vcol = col - 2048;
        int h = vcol >> 6, d = vcol & 63;
        int rowg0 = m0 + wr * 128 + m * 16 + l4 * 4;
        int b = rowg0 >> 10, tok = rowg0 & 1023;
        *reinterpret_cast<ushort4*>(
            vTout + (((size_t)(b * 16 + h) * 64 + d) << 10) + tok) = vq;
      }
    }
  }
}

// ---------------- split-K reduce (bf16 partials + bf16 residual) + te passthrough ----------------
__global__ __launch_bounds__(256) void reduce4_kernel(
    const u16* __restrict__ part, const u16* __restrict__ x2,
    const float* __restrict__ bias, const float* __restrict__ te,
    float* __restrict__ out) {
  size_t i = (size_t)blockIdx.x * 256 + threadIdx.x;
  const size_t MN = (size_t)4096 * 1024;
  ushort4 xr = reinterpret_cast<const ushort4*>(x2)[i];
  int col = (int)((i * 4) & 1023);
  float4 bv = *reinterpret_cast<const float4*>(&bias[col]);
  float a0 = bf2f(xr.x) + bv.x, a1 = bf2f(xr.y) + bv.y;
  float a2 = bf2f(xr.z) + bv.z, a3 = bf2f(xr.w) + bv.w;
  #pragma unroll
  for (int p = 0; p < 4; ++p) {
    ushort4 u = reinterpret_cast<const ushort4*>(part + p * MN)[i];
    a0 += bf2f(u.x); a1 += bf2f(u.y); a2 += bf2f(u.z); a3 += bf2f(u.w);
  }
  float4 o; o.x = a0; o.y = a1; o.z = a2; o.w = a3;
  reinterpret_cast<float4*>(out)[i] = o;
  if (blockIdx.x < 16) {
    int ii = blockIdx.x * 256 + threadIdx.x;
    out[4096 * 1024 + ii] = te[ii];
  }
}

// ---------------- flash attention: swapped QK^T, fully in-register softmax/P ----------------
__global__ __launch_bounds__(256, 4) void attn_kernel(
    const u16* __restrict__ qkv, const u16* __restrict__ vT, u16* __restrict__ out) {
  __shared__ __align__(16) u16 Ks[2][4096];
  __shared__ __align__(16) u16 Vs[2][4096];
  int tid = threadIdx.x, wid = tid >> 6, lane = tid & 63;
  int l15 = lane & 15, l4 = lane >> 4;
  int L = blockIdx.y * gridDim.x + blockIdx.x;
  int qt = (L >> 3) & 15;
  int bh = (L & 7) | ((L >> 7) << 3);
  int b = bh >> 4, h = bh & 15;
  const size_t SN = 3 * DH;
  const u16* qb = qkv + (size_t)b * NN * SN + h * HD;
  const u16* kb = qb + DH;
  const u16* vtb = vT + (size_t)bh * 64 * 1024;

  int qrow = qt * 64 + wid * 16 + l15;
  bf16x8 qf[2];
  #pragma unroll
  for (int ks = 0; ks < 2; ++ks)
    qf[ks] = *reinterpret_cast<const bf16x8*>(qb + (size_t)qrow * SN + ks * 32 + l4 * 8);

  float m_ = -1e30f, l_ = 0.f;
  f32x4 o_[4] = {};

  int laA = ((l4 * 2) & 3) * 16 + l15;
  int laB = ((l4 * 2 + 1) & 3) * 16 + l15;
  bool nbhi = (l4 >> 1) != 0;

  int iA = tid, iB = 256 + tid;
  int jA = iA >> 3, sA = iA & 7, gsA = sA ^ (jA & 7);
  int jB = iB >> 3, sB = iB & 7, gsB = sB ^ (jB & 7);

  auto stageKV = [&](int bufn, int t) {
    const u16* kt = kb + (size_t)t * 64 * SN;
    async16(kt + (size_t)jA * SN + gsA * 8, &Ks[bufn][iA * 8]);
    async16(kt + (size_t)jB * SN + gsB * 8, &Ks[bufn][iB * 8]);
    const u16* vt = vtb + (size_t)t * 64;
    async16(vt + (size_t)jA * 1024 + gsA * 8, &Vs[bufn][iA * 8]);
    async16(vt + (size_t)jB * 1024 + gsB * 8, &Vs[bufn][iB * 8]);
  };

  stageKV(0, 0);
  __syncthreads();

  int buf = 0;
  for (int t = 0; t < 16; ++t) {
    if (t < 15) stageKV(buf ^ 1, t + 1);

    f32x4 sa[4];
    #pragma unroll
    for (int nb = 0; nb < 4; ++nb) {
      f32x4 s = {};
      #pragma unroll
      for (int ks = 0; ks < 2; ++ks) {
        int j = nb * 16 + l15;
        int ps = (ks * 4 + l4) ^ (j & 7);
        bf16x8 kf = *reinterpret_cast<const bf16x8*>(&Ks[buf][j * 64 + ps * 8]);
        s = MFMA16(kf, qf[ks], s);
      }
      sa[nb] = s * 0.125f;
    }

    float pm = sa[0][0];
    #pragma unroll
    for (int nb = 0; nb < 4; ++nb)
      #pragma unroll
      for (int r = 0; r < 4; ++r)
        if (nb || r) pm = fmaxf(pm, sa[nb][r]);
    pm = fmaxf(pm, __shfl_xor(pm, 16));
    pm = fmaxf(pm, __shfl_xor(pm, 32));

    if (!__all(pm - m_ <= 8.f)) {
      float mn = fmaxf(m_, pm);
      float corr = __expf(m_ - mn);
      m_ = mn;
      l_ *= corr;
      float c0 = __shfl(corr, l4 * 4 + 0);
      float c1 = __shfl(corr, l4 * 4 + 1);
      float c2 = __shfl(corr, l4 * 4 + 2);
      float c3 = __shfl(corr, l4 * 4 + 3);
      #pragma unroll
      for (int nd = 0; nd < 4; ++nd) {
        o_[nd][0] *= c0; o_[nd][1] *= c1; o_[nd][2] *= c2; o_[nd][3] *= c3;
      }
    }

    float ts = 0.f;
    u32 pk[4][2];
    #pragma unroll
    for (int nb = 0; nb < 4; ++nb) {
      float p0 = __expf(sa[nb][0] - m_);
      float p1 = __expf(sa[nb][1] - m_);
      float p2 = __expf(sa[nb][2] - m_);
      float p3 = __expf(sa[nb][3] - m_);
      ts += (p0 + p1) + (p2 + p3);
      pk[nb][0] = (u32)f2bf(p0) | ((u32)f2bf(p1) << 16);
      pk[nb][1] = (u32)f2bf(p2) | ((u32)f2bf(p3) << 16);
    }
    ts += __shfl_xor(ts, 16);
    ts += __shfl_xor(ts, 32);
    l_ += ts;

    __builtin_amdgcn_s_setprio(1);
    #pragma unroll
    for (int ks = 0; ks < 2; ++ks) {
      int nlo = ks * 2, nhi = ks * 2 + 1;
      u32 a00 = __shfl((int)pk[nlo][0], laA), a01 = __shfl((int)pk[nlo][1], laA);
      u32 a10 = __shfl((int)pk[nhi][0], laA), a11 = __shfl((int)pk[nhi][1], laA);
      u32 b00 = __shfl((int)pk[nlo][0], laB), b01 = __shfl((int)pk[nlo][1], laB);
      u32 b10 = __shfl((int)pk[nhi][0], laB), b11 = __shfl((int)pk[nhi][1], laB);
      u32x4 wv;
      wv[0] = nbhi ? a10 : a00;
      wv[1] = nbhi ? a11 : a01;
      wv[2] = nbhi ? b10 : b00;
      wv[3] = nbhi ? b11 : b01;
      bf16x8 pa = __builtin_bit_cast(bf16x8, wv);
      #pragma unroll
      for (int nd = 0; nd < 4; ++nd) {
        int d = nd * 16 + l15;
        int psv = (ks * 4 + l4) ^ (d & 7);
        bf16x8 vf = *reinterpret_cast<const bf16x8*>(&Vs[buf][d * 64 + psv * 8]);
        o_[nd] = MFMA16(pa, vf, o_[nd]);
      }
    }
    __builtin_amdgcn_s_setprio(0);

    if (t < 15) __syncthreads();
    buf ^= 1;
  }

  float li0 = __shfl(l_, l4 * 4 + 0);
  float li1 = __shfl(l_, l4 * 4 + 1);
  float li2 = __shfl(l_, l4 * 4 + 2);
  float li3 = __shfl(l_, l4 * 4 + 3);
  float inv[4] = { 1.f / li0, 1.f / li1, 1.f / li2, 1.f / li3 };
  u16* ob = out + (size_t)b * NN * DH + h * HD;
  #pragma unroll
  for (int nd = 0; nd < 4; ++nd) {
    #pragma unroll
    for (int r = 0; r < 4; ++r) {
      int q = qt * 64 + wid * 16 + l4 * 4 + r;
      ob[(size_t)q * DH + nd * 16 + l15] = f2bf(o_[nd][r] * inv[r]);
    }
  }
}

extern "C" void kernel_launch(void* const* d_in, const int* in_sizes, int n_in,
                              void* d_out, int out_size, void* d_ws, size_t ws_size,
                              hipStream_t stream) {
  (void)in_sizes; (void)n_in; (void)out_size; (void)ws_size;
  const float* x      = (const float*)d_in[0];
  const float* te     = (const float*)d_in[1];
  const float* ln1_g  = (const float*)d_in[2];
  const float* ln1_b  = (const float*)d_in[3];
  const float* s1_w   = (const float*)d_in[4];
  const float* s1_b   = (const float*)d_in[5];
  const float* o1_w   = (const float*)d_in[6];
  const float* o1_b   = (const float*)d_in[7];
  const float* qkv_w  = (const float*)d_in[8];
  const float* qkv_b  = (const float*)d_in[9];
  const float* proj_w = (const float*)d_in[10];
  const float* proj_b = (const float*)d_in[11];
  const float* ln2_g  = (const float*)d_in[12];
  const float* ln2_b  = (const float*)d_in[13];
  const float* s2_w   = (const float*)d_in[14];
  const float* s2_b   = (const float*)d_in[15];
  const float* o2_w   = (const float*)d_in[16];
  const float* o2_b   = (const float*)d_in[17];
  const float* up_w   = (const float*)d_in[18];
  const float* up_b   = (const float*)d_in[19];
  const float* down_w = (const float*)d_in[20];
  const float* down_b = (const float*)d_in[21];

  char* ws = (char*)d_ws;
  size_t off = 0;
  auto alloc = [&](size_t bytes) { void* p = ws + off; off += (bytes + 255) & ~255ull; return p; };
  u16*   wq   = (u16*)  alloc((size_t)3072 * 1024 * 2);
  u16*   wp   = (u16*)  alloc((size_t)1024 * 1024 * 2);
  u16*   wu   = (u16*)  alloc((size_t)4096 * 1024 * 2);
  u16*   h1   = (u16*)  alloc((size_t)4096 * 1024 * 2);
  u16*   qkvb = (u16*)  alloc((size_t)4096 * 3072 * 2);
  u16*   att  = (u16*)  alloc((size_t)4096 * 1024 * 2);
  u16*   h2   = (u16*)  alloc((size_t)4096 * 1024 * 2);
  u16*   wd   = (u16*)  alloc((size_t)1024 * 4096 * 2);
  u16*   x2b  = (u16*)  alloc((size_t)4096 * 1024 * 2);   // bf16 residual stream
  u16*   upb  = (u16*)  alloc((size_t)4096 * 4096 * 2);
  u16*   vT   = (u16*)  alloc((size_t)64 * 64 * 1024 * 2);   // written by qkv epilogue
  float* ada  = (float*)alloc((size_t)4 * 4 * 1024 * 4);
  float* sp1 = ada, *off1 = ada + 4096, *sp2 = ada + 8192, *off2 = ada + 12288;
  u16*   part = wq;   // overlays dead region (wq dead after qkv GEMM)

  cvt_all_kernel<<<12288, 256, 0, stream>>>(qkv_w, proj_w, up_w, down_w, wq, wp, wu, wd);
  adaln_kernel<<<dim3(256, 4), 256, 0, stream>>>(te, s1_w, s1_b, o1_w, o1_b, s2_w, s2_b, o2_w, o2_b, ada);
  ln_mod_kernel<<<4096, 256, 0, stream>>>(x, ln1_g, ln1_b, sp1, off1, h1);
  gemmT_kernel<EPI_BF16V><<<dim3(24, 16, 1), 512, 73728, stream>>>(h1, wq, qkv_b, nullptr, qkvb, vT, 3072, 1024);
  attn_kernel<<<dim3(16, 64), 256, 0, stream>>>(qkvb, vT, att);
  gemmT_kernel<EPI_RES><<<dim3(8, 16, 1), 512, 73728, stream>>>(att, wp, proj_b, x, x2b, nullptr, 1024, 1024);
  ln_mod_bf16_kernel<<<4096, 256, 0, stream>>>(x2b, ln2_g, ln2_b, sp2, off2, h2);
  gemmT_kernel<EPI_GELU><<<dim3(32, 16, 1), 512, 73728, stream>>>(h2, wu, up_b, nullptr, upb, nullptr, 4096, 1024);
  gemmT_kernel<EPI_PART><<<dim3(8, 16, 4), 512, 73728, stream>>>(upb, wd, nullptr, nullptr, part, nullptr, 1024, 4096);
  reduce4_kernel<<<4096, 256, 0, stream>>>(part, x2b, down_b, te, (float*)d_out);
}